// Round 9
// baseline (310.865 us; speedup 1.0000x reference)
//
#include <hip/hip_runtime.h>
#include <hip/hip_bf16.h>

typedef float f32x4 __attribute__((ext_vector_type(4)));
typedef __bf16 bf16x8 __attribute__((ext_vector_type(8)));

static __device__ __forceinline__ unsigned short f2bf(float f) {
    unsigned int u = __float_as_uint(f);
    unsigned int r = (u + 0x7fffu + ((u >> 16) & 1u)) >> 16;   // RNE
    return (unsigned short)r;
}

// async global->LDS, 16B per lane; LDS dest = wave-uniform base + lane*16
static __device__ __forceinline__ void gll16(const void* g, void* l) {
    __builtin_amdgcn_global_load_lds(
        (const __attribute__((address_space(1))) unsigned int*)g,
        (__attribute__((address_space(3))) unsigned int*)l, 16, 0, 0);
}

// ---------------------------------------------------------------------------
// prep: pack both conv weights (tile-major MFMA-ready) + cumsum + idx-expand.
// Pack dest: for (n, cin, kk): kt=kk*8+(cin>>5); j = kt*8192 + (n>>4)*512
//            + (((cin>>3)&3)*16 + (n&15))*8 + (cin&7).  Coalesced reads.
// ---------------------------------------------------------------------------
__global__ __launch_bounds__(512) void prep(
    const float* __restrict__ w1, const float* __restrict__ w2,
    unsigned short* __restrict__ w1p, unsigned short* __restrict__ w2p,
    const int* __restrict__ tgt, short* __restrict__ idxT, int M)
{
    int blk = blockIdx.x;
    if (blk < 256) {
        int gi = blk * 512 + threadIdx.x;            // 0..131071 (pair index)
        const float* w = (gi < 65536) ? w1 : w2;
        unsigned short* wp = (gi < 65536) ? w1p : w2p;
        int p = gi & 65535;
        int n = p >> 8, cin = p & 255;
        const float* src = w + (size_t)p * 3;
        float a[3] = {src[0], src[1], src[2]};
        int nb = n >> 4, nl = n & 15;
        int e = cin & 7, lhi = (cin >> 3) & 3, chi = cin >> 5;
        int base = nb * 512 + (lhi * 16 + nl) * 8 + e;
        #pragma unroll
        for (int kk = 0; kk < 3; ++kk)
            wp[(kk * 8 + chi) * 8192 + base] = f2bf(a[kk]);
    } else {
        __shared__ int s[512];
        int b = blk - 256, tid = threadIdx.x;
        int d = tgt[b * 512 + tid];
        s[tid] = d;
        __syncthreads();
        for (int off = 1; off < 512; off <<= 1) {
            int v = (tid >= off) ? s[tid - off] : 0;
            __syncthreads();
            s[tid] += v;
            __syncthreads();
        }
        int myend = s[tid];          // inclusive cumsum
        int mystart = myend - d;
        short* row = idxT + (size_t)b * M;
        for (int p = mystart; p < myend; ++p) row[p] = (short)tid;
        __syncthreads();
        int total = s[511];
        for (int p = total + tid; p < M; p += 512) row[p] = (short)-1;
    }
}

// ---------------------------------------------------------------------------
// gather part: 32 mel rows / block, 8 waves; direct idx lookup, NT stores
// ---------------------------------------------------------------------------
static __device__ __forceinline__ void gather_part(
    int gblk, int phase, const float* __restrict__ x, const short* __restrict__ idxT,
    float* __restrict__ out, int M, int wv, int lane)
{
    int b = gblk / 56;
    int r0 = (gblk % 56) * 32 + phase;
    const short* row = idxT + (size_t)b * M;
    int id[4];
    #pragma unroll
    for (int i = 0; i < 4; ++i) id[i] = row[r0 + i * 8 + wv];
    #pragma unroll
    for (int i = 0; i < 4; ++i) {
        int m = r0 + i * 8 + wv;
        f32x4 v = {0.f, 0.f, 0.f, 0.f};
        if (id[i] >= 0)
            v = *reinterpret_cast<const f32x4*>(x + ((size_t)(b * 512 + id[i])) * 256 + lane * 4);
        __builtin_nontemporal_store(
            v, reinterpret_cast<f32x4*>(out + ((size_t)b * M + m) * 256 + lane * 4));
    }
}

// ---------------------------------------------------------------------------
// conv1 + gather(first half). BM=64, BN=256, BK=32 (24 tiles), 8 waves 2Mx4N.
// Double-buffered B staging (round-6 structure).
// ---------------------------------------------------------------------------
template<int REP>
__global__ __launch_bounds__(512, 4) void conv1_hetero(
    const float* __restrict__ x, const unsigned short* __restrict__ Wp,
    const float* __restrict__ bias, const float* __restrict__ g,
    const float* __restrict__ be, unsigned short* __restrict__ h1b,
    const short* __restrict__ idxT, float* __restrict__ out, int M)
{
    __shared__ __align__(16) unsigned short As[66 * 256];
    __shared__ __align__(16) unsigned short Bsm[2][8192];
    __shared__ float lnS[4][64], lnQ[4][64];

    const int tid = threadIdx.x;
    const int lane = tid & 63;
    const int wv = tid >> 6;

    if (blockIdx.x >= 256) {
        for (int rep = 0; rep < REP; ++rep) {
            gather_part(blockIdx.x - 256, 0, x, idxT, out, M, wv, lane);
            asm volatile("" ::: "memory");
        }
        return;
    }

    const int wmi = wv >> 2, wni = wv & 3;
    const int grp = lane >> 4, lr = lane & 15;
    const int b = blockIdx.x >> 3;
    const int t_base = (blockIdx.x & 7) * 64;

    const char* wpB = (const char*)Wp;
    char* bs0 = (char*)&Bsm[0][0];
    #define STAGE_B(kt, buf) do {                                              \
        const char* _s = wpB + (kt) * 16384 + wv * 2048 + lane * 16;           \
        char* _d = bs0 + (buf) * 16384 + wv * 2048;                            \
        gll16(_s, _d); gll16(_s + 1024, _d + 1024);                            \
    } while (0)

    for (int rep = 0; rep < REP; ++rep) {
        __syncthreads();   // protect As/Bsm reuse across reps (no-op at REP=1 start)

        // ---- A stage: x rows t_base-1 .. t_base+64 -> bf16, XOR-swizzled
        #pragma unroll
        for (int i = 0; i < 9; ++i) {
            int cc = i * 512 + tid;
            if (cc < 66 * 64) {
                int row = cc >> 6, q = cc & 63;
                int tt = t_base - 1 + row;
                ushort4 o = make_ushort4(0, 0, 0, 0);
                if ((unsigned)tt < 512u) {
                    float4 v = *reinterpret_cast<const float4*>(x + ((size_t)(b * 512 + tt)) * 256 + q * 4);
                    o.x = f2bf(v.x); o.y = f2bf(v.y); o.z = f2bf(v.z); o.w = f2bf(v.w);
                }
                *reinterpret_cast<ushort4*>(&As[row * 256 + ((q * 4) ^ ((row & 7) << 3))]) = o;
            }
        }

        STAGE_B(0, 0);
        __syncthreads();

        f32x4 acc[2][4] = {};
        int cur = 0;
        for (int kt = 0; kt < 24; ++kt) {
            if (kt < 23) STAGE_B(kt + 1, cur ^ 1);
            const int kk = kt >> 3, cin0 = (kt & 7) * 32;
            bf16x8 af[2], bfr[4];
            #pragma unroll
            for (int mi = 0; mi < 2; ++mi) {
                int tr = wmi * 32 + mi * 16 + lr + kk;
                af[mi] = *reinterpret_cast<const bf16x8*>(&As[tr * 256 + ((cin0 + grp * 8) ^ ((tr & 7) << 3))]);
            }
            #pragma unroll
            for (int ni = 0; ni < 4; ++ni)
                bfr[ni] = *reinterpret_cast<const bf16x8*>(&Bsm[cur][(wni * 4 + ni) * 512 + lane * 8]);
            __builtin_amdgcn_s_setprio(1);
            #pragma unroll
            for (int mi = 0; mi < 2; ++mi)
                #pragma unroll
                for (int ni = 0; ni < 4; ++ni)
                    acc[mi][ni] = __builtin_amdgcn_mfma_f32_16x16x32_bf16(af[mi], bfr[ni], acc[mi][ni], 0, 0, 0);
            __builtin_amdgcn_s_setprio(0);
            __syncthreads();
            cur ^= 1;
        }

        // ---- epilogue: bias+relu, LN, LDS-staged vectorized bf16 store
        float bcol[4], gcol[4], becol[4];
        #pragma unroll
        for (int ni = 0; ni < 4; ++ni) {
            int col = wni * 64 + ni * 16 + lr;
            bcol[ni] = bias[col]; gcol[ni] = g[col]; becol[ni] = be[col];
        }
        #pragma unroll
        for (int mi = 0; mi < 2; ++mi)
            #pragma unroll
            for (int ni = 0; ni < 4; ++ni)
                #pragma unroll
                for (int r = 0; r < 4; ++r)
                    acc[mi][ni][r] = fmaxf(acc[mi][ni][r] + bcol[ni], 0.f);

        #pragma unroll
        for (int mi = 0; mi < 2; ++mi)
            #pragma unroll
            for (int r = 0; r < 4; ++r) {
                float s = acc[mi][0][r] + acc[mi][1][r] + acc[mi][2][r] + acc[mi][3][r];
                float q = acc[mi][0][r] * acc[mi][0][r] + acc[mi][1][r] * acc[mi][1][r]
                        + acc[mi][2][r] * acc[mi][2][r] + acc[mi][3][r] * acc[mi][3][r];
                #pragma unroll
                for (int off = 1; off < 16; off <<= 1) {
                    s += __shfl_xor(s, off);
                    q += __shfl_xor(q, off);
                }
                if (lr == 0) {
                    int R = wmi * 32 + mi * 16 + grp * 4 + r;
                    lnS[wni][R] = s; lnQ[wni][R] = q;
                }
            }
        __syncthreads();

        unsigned short* Hs = &Bsm[0][0];   // 32 KB, dead after K-loop
        #pragma unroll
        for (int mi = 0; mi < 2; ++mi)
            #pragma unroll
            for (int r = 0; r < 4; ++r) {
                int R = wmi * 32 + mi * 16 + grp * 4 + r;
                float mu = (lnS[0][R] + lnS[1][R] + lnS[2][R] + lnS[3][R]) * (1.f / 256.f);
                float var = (lnQ[0][R] + lnQ[1][R] + lnQ[2][R] + lnQ[3][R]) * (1.f / 256.f) - mu * mu;
                float rs = rsqrtf(var + 1e-5f);
                #pragma unroll
                for (int ni = 0; ni < 4; ++ni) {
                    int col = wni * 64 + ni * 16 + lr;
                    float h = (acc[mi][ni][r] - mu) * rs * gcol[ni] + becol[ni];
                    Hs[R * 256 + (col ^ ((R & 7) << 3))] = f2bf(h);   // conv2's swizzle
                }
            }
        __syncthreads();
        #pragma unroll
        for (int i = 0; i < 4; ++i) {
            int c = i * 512 + tid;          // 2048 chunks of 16B
            int row = c >> 5, seg = c & 31;
            uint4 v = *reinterpret_cast<const uint4*>(&Hs[row * 256 + seg * 8]);
            *reinterpret_cast<uint4*>(h1b + ((size_t)(b * 512 + t_base + row)) * 256 + seg * 8) = v;
        }
        asm volatile("" ::: "memory");
    }
    #undef STAGE_B
}

// ---------------------------------------------------------------------------
// conv2 + LN + linear + relu -> dur, + gather(second half)
// ---------------------------------------------------------------------------
template<int REP>
__global__ __launch_bounds__(512, 4) void conv2_hetero(
    const unsigned short* __restrict__ h1b, const unsigned short* __restrict__ Wp,
    const float* __restrict__ bias, const float* __restrict__ g,
    const float* __restrict__ be, const float* __restrict__ lw,
    const float* __restrict__ lb, float* __restrict__ dur,
    const short* __restrict__ idxT, const float* __restrict__ x,
    float* __restrict__ out, int M)
{
    __shared__ __align__(16) unsigned short As[66 * 256];
    __shared__ __align__(16) unsigned short Bsm[2][8192];
    __shared__ float lnS[4][64], lnQ[4][64], lnD[4][64];

    const int tid = threadIdx.x;
    const int lane = tid & 63;
    const int wv = tid >> 6;

    if (blockIdx.x >= 256) {
        for (int rep = 0; rep < REP; ++rep) {
            gather_part(blockIdx.x - 256, 1792, x, idxT, out, M, wv, lane);
            asm volatile("" ::: "memory");
        }
        return;
    }

    const int wmi = wv >> 2, wni = wv & 3;
    const int grp = lane >> 4, lr = lane & 15;
    const int b = blockIdx.x >> 3;
    const int t_base = (blockIdx.x & 7) * 64;

    const char* wpB = (const char*)Wp;
    char* bs0 = (char*)&Bsm[0][0];
    #define STAGE_B(kt, buf) do {                                              \
        const char* _s = wpB + (kt) * 16384 + wv * 2048 + lane * 16;           \
        char* _d = bs0 + (buf) * 16384 + wv * 2048;                            \
        gll16(_s, _d); gll16(_s + 1024, _d + 1024);                            \
    } while (0)

    for (int rep = 0; rep < REP; ++rep) {
        __syncthreads();

        // ---- A stage: interior rows 1..64 via global_load_lds (pre-swizzled)
        {
            const char* src = (const char*)h1b + ((size_t)(b * 512 + t_base)) * 512 + wv * 4096 + lane * 16;
            char* dst = (char*)&As[256] + wv * 4096;
            #pragma unroll
            for (int i = 0; i < 4; ++i) gll16(src + i * 1024, dst + i * 1024);
        }
        // halo rows 0 (t_base-1) and 65 (t_base+64), zero-padded
        if (tid < 32) {
            int tt = t_base - 1;
            uint4 v = make_uint4(0u, 0u, 0u, 0u);
            if (tt >= 0)
                v = *reinterpret_cast<const uint4*>((const char*)h1b + ((size_t)(b * 512 + tt)) * 512 + tid * 16);
            *reinterpret_cast<uint4*>((char*)As + tid * 16) = v;
        } else if (tid < 64) {
            int t2 = tid - 32, tt = t_base + 64;
            uint4 v = make_uint4(0u, 0u, 0u, 0u);
            if (tt < 512)
                v = *reinterpret_cast<const uint4*>((const char*)h1b + ((size_t)(b * 512 + tt)) * 512 + t2 * 16);
            *reinterpret_cast<uint4*>((char*)&As[65 * 256] + t2 * 16) = v;
        }

        STAGE_B(0, 0);
        __syncthreads();

        f32x4 acc[2][4] = {};
        int cur = 0;
        for (int kt = 0; kt < 24; ++kt) {
            if (kt < 23) STAGE_B(kt + 1, cur ^ 1);
            const int kk = kt >> 3, cin0 = (kt & 7) * 32;
            bf16x8 af[2], bfr[4];
            #pragma unroll
            for (int mi = 0; mi < 2; ++mi) {
                int tr = wmi * 32 + mi * 16 + lr + kk;
                // h1b swizzle follows absolute t = t_base + tr - 1 -> bits (tr+7)&7
                af[mi] = *reinterpret_cast<const bf16x8*>(&As[tr * 256 + ((cin0 + grp * 8) ^ (((tr + 7) & 7) << 3))]);
            }
            #pragma unroll
            for (int ni = 0; ni < 4; ++ni)
                bfr[ni] = *reinterpret_cast<const bf16x8*>(&Bsm[cur][(wni * 4 + ni) * 512 + lane * 8]);
            __builtin_amdgcn_s_setprio(1);
            #pragma unroll
            for (int mi = 0; mi < 2; ++mi)
                #pragma unroll
                for (int ni = 0; ni < 4; ++ni)
                    acc[mi][ni] = __builtin_amdgcn_mfma_f32_16x16x32_bf16(af[mi], bfr[ni], acc[mi][ni], 0, 0, 0);
            __builtin_amdgcn_s_setprio(0);
            __syncthreads();
            cur ^= 1;
        }

        // ---- epilogue: bias+relu, LN, dot lin_w, relu -> dur[64]
        float bcol[4], gcol[4], becol[4], wcol[4];
        #pragma unroll
        for (int ni = 0; ni < 4; ++ni) {
            int col = wni * 64 + ni * 16 + lr;
            bcol[ni] = bias[col]; gcol[ni] = g[col]; becol[ni] = be[col]; wcol[ni] = lw[col];
        }
        #pragma unroll
        for (int mi = 0; mi < 2; ++mi)
            #pragma unroll
            for (int ni = 0; ni < 4; ++ni)
                #pragma unroll
                for (int r = 0; r < 4; ++r)
                    acc[mi][ni][r] = fmaxf(acc[mi][ni][r] + bcol[ni], 0.f);

        #pragma unroll
        for (int mi = 0; mi < 2; ++mi)
            #pragma unroll
            for (int r = 0; r < 4; ++r) {
                float s = acc[mi][0][r] + acc[mi][1][r] + acc[mi][2][r] + acc[mi][3][r];
                float q = acc[mi][0][r] * acc[mi][0][r] + acc[mi][1][r] * acc[mi][1][r]
                        + acc[mi][2][r] * acc[mi][2][r] + acc[mi][3][r] * acc[mi][3][r];
                #pragma unroll
                for (int off = 1; off < 16; off <<= 1) {
                    s += __shfl_xor(s, off);
                    q += __shfl_xor(q, off);
                }
                if (lr == 0) {
                    int R = wmi * 32 + mi * 16 + grp * 4 + r;
                    lnS[wni][R] = s; lnQ[wni][R] = q;
                }
            }
        __syncthreads();
        #pragma unroll
        for (int mi = 0; mi < 2; ++mi)
            #pragma unroll
            for (int r = 0; r < 4; ++r) {
                int R = wmi * 32 + mi * 16 + grp * 4 + r;
                float mu = (lnS[0][R] + lnS[1][R] + lnS[2][R] + lnS[3][R]) * (1.f / 256.f);
                float var = (lnQ[0][R] + lnQ[1][R] + lnQ[2][R] + lnQ[3][R]) * (1.f / 256.f) - mu * mu;
                float rs = rsqrtf(var + 1e-5f);
                float d = ((acc[mi][0][r] - mu) * rs * gcol[0] + becol[0]) * wcol[0]
                        + ((acc[mi][1][r] - mu) * rs * gcol[1] + becol[1]) * wcol[1]
                        + ((acc[mi][2][r] - mu) * rs * gcol[2] + becol[2]) * wcol[2]
                        + ((acc[mi][3][r] - mu) * rs * gcol[3] + becol[3]) * wcol[3];
                #pragma unroll
                for (int off = 1; off < 16; off <<= 1) d += __shfl_xor(d, off);
                if (lr == 0) lnD[wni][R] = d;
            }
        __syncthreads();
        if (tid < 64) {
            float dd = lnD[0][tid] + lnD[1][tid] + lnD[2][tid] + lnD[3][tid] + lb[0];
            dur[(size_t)b * 512 + t_base + tid] = fmaxf(dd, 0.f);
        }
        asm volatile("" ::: "memory");
    }
    #undef STAGE_B
}

extern "C" void kernel_launch(void* const* d_in, const int* in_sizes, int n_in,
                              void* d_out, int out_size, void* d_ws, size_t ws_size,
                              hipStream_t stream) {
    const float* x   = (const float*)d_in[0];
    const float* w1  = (const float*)d_in[1];
    const float* b1  = (const float*)d_in[2];
    const float* g1  = (const float*)d_in[3];
    const float* be1 = (const float*)d_in[4];
    const float* w2  = (const float*)d_in[5];
    const float* b2  = (const float*)d_in[6];
    const float* g2  = (const float*)d_in[7];
    const float* be2 = (const float*)d_in[8];
    const float* lw  = (const float*)d_in[9];
    const float* lb  = (const float*)d_in[10];
    const int* tgt   = (const int*)d_in[11];
    float* out = (float*)d_out;

    const int B = 32, T = 512, C = 256;
    const int rows = B * T;                       // 16384
    const int M = (out_size - rows) / (B * C);    // 3584

    char* ws = (char*)d_ws;
    unsigned short* w1p = (unsigned short*)(ws);              //   393,216 B
    unsigned short* w2p = (unsigned short*)(ws + 393216);     //   393,216 B
    unsigned short* h1b = (unsigned short*)(ws + 786432);     // 8,388,608 B
    short* idxT         = (short*)(ws + 9175040);             //   229,376 B

    // ---- real pipeline (round-6 structure + NT gather + coalesced prep) ----
    prep<<<288, 512, 0, stream>>>(w1, w2, w1p, w2p, tgt, idxT, M);
    conv1_hetero<1><<<2048, 512, 0, stream>>>(x, w1p, b1, g1, be1, h1b, idxT, out, M);
    conv2_hetero<1><<<2048, 512, 0, stream>>>(h1b, w2p, b2, g2, be2, lw, lb,
                                              out + (size_t)B * M * C, idxT, x, out, M);

    // ---- idempotent amplified probes (warm per-kernel counters) ----
    conv1_hetero<4><<<2048, 512, 0, stream>>>(x, w1p, b1, g1, be1, h1b, idxT, out, M);
    conv2_hetero<4><<<2048, 512, 0, stream>>>(h1b, w2p, b2, g2, be2, lw, lb,
                                              out + (size_t)B * M * C, idxT, x, out, M);
}

// Round 10
// 99.285 us; speedup vs baseline: 3.1310x; 3.1310x over previous
//
#include <hip/hip_runtime.h>
#include <hip/hip_bf16.h>

typedef float f32x4 __attribute__((ext_vector_type(4)));
typedef __bf16 bf16x8 __attribute__((ext_vector_type(8)));

static __device__ __forceinline__ unsigned short f2bf(float f) {
    unsigned int u = __float_as_uint(f);
    unsigned int r = (u + 0x7fffu + ((u >> 16) & 1u)) >> 16;   // RNE
    return (unsigned short)r;
}

// async global->LDS, 16B per lane; LDS dest = wave-uniform base + lane*16,
// global src is PER-LANE.
static __device__ __forceinline__ void gll16(const void* g, void* l) {
    __builtin_amdgcn_global_load_lds(
        (const __attribute__((address_space(1))) unsigned int*)g,
        (__attribute__((address_space(3))) unsigned int*)l, 16, 0, 0);
}

// ---------------------------------------------------------------------------
// prep: pack conv weights (tile-major MFMA-ready) + cumsum + idx-expand.
// Within tile ktg = kk*8 + (cin>>5): ushort off = (nb*64+l)*8+e,
//   n = nb*16 + (l&15), k_local = (l>>4)*8 + e.
// ---------------------------------------------------------------------------
__global__ __launch_bounds__(512) void prep(
    const float* __restrict__ w1, const float* __restrict__ w2,
    unsigned short* __restrict__ w1p, unsigned short* __restrict__ w2p,
    const int* __restrict__ tgt, short* __restrict__ idxT, int M)
{
    int blk = blockIdx.x;
    if (blk < 256) {
        int gi = blk * 512 + threadIdx.x;            // pair index
        const float* w = (gi < 65536) ? w1 : w2;
        unsigned short* wp = (gi < 65536) ? w1p : w2p;
        int p = gi & 65535;
        int n = p >> 8, cin = p & 255;
        const float* src = w + (size_t)p * 3;
        float a[3] = {src[0], src[1], src[2]};
        int nb = n >> 4, nl = n & 15;
        int e = cin & 7, lhi = (cin >> 3) & 3, chi = cin >> 5;
        int base = nb * 512 + (lhi * 16 + nl) * 8 + e;
        #pragma unroll
        for (int kk = 0; kk < 3; ++kk)
            wp[(kk * 8 + chi) * 8192 + base] = f2bf(a[kk]);
    } else {
        __shared__ int s[512];
        int b = blk - 256, tid = threadIdx.x;
        int d = tgt[b * 512 + tid];
        s[tid] = d;
        __syncthreads();
        for (int off = 1; off < 512; off <<= 1) {
            int v = (tid >= off) ? s[tid - off] : 0;
            __syncthreads();
            s[tid] += v;
            __syncthreads();
        }
        int myend = s[tid];
        int mystart = myend - d;
        short* row = idxT + (size_t)b * M;
        for (int p = mystart; p < myend; ++p) row[p] = (short)tid;
        __syncthreads();
        int total = s[511];
        for (int p = total + tid; p < M; p += 512) row[p] = (short)-1;
    }
}

// ---------------------------------------------------------------------------
// gather part: 32 mel rows / block, 8 waves; idx lookup, NT stores
// ---------------------------------------------------------------------------
static __device__ __forceinline__ void gather_part(
    int gblk, int phase, const float* __restrict__ x, const short* __restrict__ idxT,
    float* __restrict__ out, int M, int wv, int lane)
{
    int b = gblk / 56;
    int r0 = (gblk % 56) * 32 + phase;
    const short* row = idxT + (size_t)b * M;
    int id[4];
    #pragma unroll
    for (int i = 0; i < 4; ++i) id[i] = row[r0 + i * 8 + wv];
    #pragma unroll
    for (int i = 0; i < 4; ++i) {
        int m = r0 + i * 8 + wv;
        f32x4 v = {0.f, 0.f, 0.f, 0.f};
        if (id[i] >= 0)
            v = *reinterpret_cast<const f32x4*>(x + ((size_t)(b * 512 + id[i])) * 256 + lane * 4);
        __builtin_nontemporal_store(
            v, reinterpret_cast<f32x4*>(out + ((size_t)b * M + m) * 256 + lane * 4));
    }
}

// ---------------------------------------------------------------------------
// conv1 + gather. BM=64, BN=256, K=768 processed as 2 cin-halves x 12 tiles.
// LDS arena: As[66][128] (16,896B) + Bs[8192] (16,384B) = 33,280B shared with
// the 32KB Hs epilogue staging. ~35.3KB total -> 4 blocks/CU.
// ---------------------------------------------------------------------------
__global__ __launch_bounds__(512, 8) void conv1_hetero(
    const float* __restrict__ x, const unsigned short* __restrict__ Wp,
    const float* __restrict__ bias, const float* __restrict__ g,
    const float* __restrict__ be, unsigned short* __restrict__ h1b,
    const short* __restrict__ idxT, float* __restrict__ out, int M)
{
    __shared__ __align__(16) unsigned short smem[16640];   // As[8448] + Bs[8192]
    __shared__ float lnS[4][64], lnQ[4][64];

    const int tid = threadIdx.x;
    const int lane = tid & 63;
    const int wv = tid >> 6;

    if (blockIdx.x >= 256) {
        gather_part(blockIdx.x - 256, 0, x, idxT, out, M, wv, lane);
        return;
    }

    unsigned short* As = smem;            // [66][128]
    unsigned short* Bs = smem + 8448;     // [8192]

    const int wmi = wv >> 2, wni = wv & 3;
    const int grp = lane >> 4, lr = lane & 15;
    const int b = blockIdx.x >> 3;
    const int t_base = (blockIdx.x & 7) * 64;

    const char* wpB = (const char*)Wp;
    #define STAGE_B(ktg) do {                                                  \
        const char* _s = wpB + (ktg) * 16384 + wv * 2048 + lane * 16;          \
        char* _d = (char*)Bs + wv * 2048;                                      \
        gll16(_s, _d); gll16(_s + 1024, _d + 1024);                            \
    } while (0)

    f32x4 acc[2][4] = {};

    for (int h = 0; h < 2; ++h) {
        // ---- A-stage: rows t_base-1..t_base+64, cin [h*128, h*128+128)
        #pragma unroll
        for (int i = 0; i < 5; ++i) {
            int cc = i * 512 + tid;                 // 2112 ushort4 chunks
            if (cc < 66 * 32) {
                int row = cc >> 5, ql = cc & 31;
                int tt = t_base - 1 + row;
                ushort4 o = make_ushort4(0, 0, 0, 0);
                if ((unsigned)tt < 512u) {
                    float4 v = *reinterpret_cast<const float4*>(
                        x + ((size_t)(b * 512 + tt)) * 256 + h * 128 + ql * 4);
                    o.x = f2bf(v.x); o.y = f2bf(v.y); o.z = f2bf(v.z); o.w = f2bf(v.w);
                }
                *reinterpret_cast<ushort4*>(&As[row * 128 + ((ql * 4) ^ ((row & 7) << 3))]) = o;
            }
        }
        STAGE_B((h * 4));                           // kk=0, cb_local=0
        __syncthreads();                            // staging visible

        for (int j = 0; j < 12; ++j) {
            const int kk = j >> 2, cbl = j & 3;
            bf16x8 af[2], bfr[4];
            #pragma unroll
            for (int mi = 0; mi < 2; ++mi) {
                int tr = wmi * 32 + mi * 16 + lr + kk;
                int cl = cbl * 32 + grp * 8;
                af[mi] = *reinterpret_cast<const bf16x8*>(&As[tr * 128 + (cl ^ ((tr & 7) << 3))]);
            }
            #pragma unroll
            for (int ni = 0; ni < 4; ++ni)
                bfr[ni] = *reinterpret_cast<const bf16x8*>(&Bs[(wni * 4 + ni) * 512 + lane * 8]);
            __syncthreads();                        // Bs reads complete
            if (j < 11) {
                int jn = j + 1;
                STAGE_B(((jn >> 2) * 8 + h * 4 + (jn & 3)));
            }
            __builtin_amdgcn_s_setprio(1);
            #pragma unroll
            for (int mi = 0; mi < 2; ++mi)
                #pragma unroll
                for (int ni = 0; ni < 4; ++ni)
                    acc[mi][ni] = __builtin_amdgcn_mfma_f32_16x16x32_bf16(af[mi], bfr[ni], acc[mi][ni], 0, 0, 0);
            __builtin_amdgcn_s_setprio(0);
            __syncthreads();                        // staging (or As reuse) safe
        }
    }

    // ---- epilogue: bias+relu, LN, LDS-staged (whole arena) bf16 store
    float bcol[4], gcol[4], becol[4];
    #pragma unroll
    for (int ni = 0; ni < 4; ++ni) {
        int col = wni * 64 + ni * 16 + lr;
        bcol[ni] = bias[col]; gcol[ni] = g[col]; becol[ni] = be[col];
    }
    #pragma unroll
    for (int mi = 0; mi < 2; ++mi)
        #pragma unroll
        for (int ni = 0; ni < 4; ++ni)
            #pragma unroll
            for (int r = 0; r < 4; ++r)
                acc[mi][ni][r] = fmaxf(acc[mi][ni][r] + bcol[ni], 0.f);

    #pragma unroll
    for (int mi = 0; mi < 2; ++mi)
        #pragma unroll
        for (int r = 0; r < 4; ++r) {
            float s = acc[mi][0][r] + acc[mi][1][r] + acc[mi][2][r] + acc[mi][3][r];
            float q = acc[mi][0][r] * acc[mi][0][r] + acc[mi][1][r] * acc[mi][1][r]
                    + acc[mi][2][r] * acc[mi][2][r] + acc[mi][3][r] * acc[mi][3][r];
            #pragma unroll
            for (int off = 1; off < 16; off <<= 1) {
                s += __shfl_xor(s, off);
                q += __shfl_xor(q, off);
            }
            if (lr == 0) {
                int R = wmi * 32 + mi * 16 + grp * 4 + r;
                lnS[wni][R] = s; lnQ[wni][R] = q;
            }
        }
    __syncthreads();

    unsigned short* Hs = smem;            // whole arena, need 16384 ushorts
    #pragma unroll
    for (int mi = 0; mi < 2; ++mi)
        #pragma unroll
        for (int r = 0; r < 4; ++r) {
            int R = wmi * 32 + mi * 16 + grp * 4 + r;
            float mu = (lnS[0][R] + lnS[1][R] + lnS[2][R] + lnS[3][R]) * (1.f / 256.f);
            float var = (lnQ[0][R] + lnQ[1][R] + lnQ[2][R] + lnQ[3][R]) * (1.f / 256.f) - mu * mu;
            float rs = rsqrtf(var + 1e-5f);
            #pragma unroll
            for (int ni = 0; ni < 4; ++ni) {
                int col = wni * 64 + ni * 16 + lr;
                float h = (acc[mi][ni][r] - mu) * rs * gcol[ni] + becol[ni];
                Hs[R * 256 + (col ^ ((R & 7) << 3))] = f2bf(h);   // conv2's swizzle
            }
        }
    __syncthreads();
    #pragma unroll
    for (int i = 0; i < 4; ++i) {
        int c = i * 512 + tid;          // 2048 chunks of 16B
        int row = c >> 5, seg = c & 31;
        uint4 v = *reinterpret_cast<const uint4*>(&Hs[row * 256 + seg * 8]);
        *reinterpret_cast<uint4*>(h1b + ((size_t)(b * 512 + t_base + row)) * 256 + seg * 8) = v;
    }
    #undef STAGE_B
}

// ---------------------------------------------------------------------------
// conv2 + LN + linear + relu -> dur, + gather(second half)
// ---------------------------------------------------------------------------
__global__ __launch_bounds__(512, 8) void conv2_hetero(
    const unsigned short* __restrict__ h1b, const unsigned short* __restrict__ Wp,
    const float* __restrict__ bias, const float* __restrict__ g,
    const float* __restrict__ be, const float* __restrict__ lw,
    const float* __restrict__ lb, float* __restrict__ dur,
    const short* __restrict__ idxT, const float* __restrict__ x,
    float* __restrict__ out, int M)
{
    __shared__ __align__(16) unsigned short smem[16640];   // As[8448] + Bs[8192]
    __shared__ float lnS[4][64], lnQ[4][64], lnD[4][64];

    const int tid = threadIdx.x;
    const int lane = tid & 63;
    const int wv = tid >> 6;

    if (blockIdx.x >= 256) {
        gather_part(blockIdx.x - 256, 1792, x, idxT, out, M, wv, lane);
        return;
    }

    unsigned short* As = smem;
    unsigned short* Bs = smem + 8448;

    const int wmi = wv >> 2, wni = wv & 3;
    const int grp = lane >> 4, lr = lane & 15;
    const int b = blockIdx.x >> 3;
    const int t_base = (blockIdx.x & 7) * 64;

    const char* wpB = (const char*)Wp;
    const char* h1B = (const char*)h1b;
    #define STAGE_B(ktg) do {                                                  \
        const char* _s = wpB + (ktg) * 16384 + wv * 2048 + lane * 16;          \
        char* _d = (char*)Bs + wv * 2048;                                      \
        gll16(_s, _d); gll16(_s + 1024, _d + 1024);                            \
    } while (0)

    f32x4 acc[2][4] = {};

    for (int h = 0; h < 2; ++h) {
        // ---- A-stage: interior rows 1..64, half h via per-lane-src gll16
        #pragma unroll
        for (int j2 = 0; j2 < 2; ++j2) {
            int row0 = 1 + wv * 8 + j2 * 4;
            const char* src = h1B
                + ((size_t)(b * 512 + t_base + wv * 8 + j2 * 4 + (lane >> 4))) * 512
                + h * 256 + (lane & 15) * 16;
            gll16(src, (char*)As + row0 * 256);
        }
        // halo rows 0 (t=t_base-1) and 65 (t=t_base+64), 256B each
        if (tid < 16) {
            int tt = t_base - 1;
            uint4 v = make_uint4(0u, 0u, 0u, 0u);
            if (tt >= 0)
                v = *reinterpret_cast<const uint4*>(h1B + ((size_t)(b * 512 + tt)) * 512 + h * 256 + tid * 16);
            *reinterpret_cast<uint4*>((char*)As + tid * 16) = v;
        } else if (tid < 32) {
            int t2 = tid - 16, tt = t_base + 64;
            uint4 v = make_uint4(0u, 0u, 0u, 0u);
            if (tt < 512)
                v = *reinterpret_cast<const uint4*>(h1B + ((size_t)(b * 512 + tt)) * 512 + h * 256 + t2 * 16);
            *reinterpret_cast<uint4*>((char*)As + 65 * 256 + t2 * 16) = v;
        }
        STAGE_B((h * 4));
        __syncthreads();

        for (int j = 0; j < 12; ++j) {
            const int kk = j >> 2, cbl = j & 3;
            bf16x8 af[2], bfr[4];
            #pragma unroll
            for (int mi = 0; mi < 2; ++mi) {
                int tr = wmi * 32 + mi * 16 + lr + kk;
                int cl = cbl * 32 + grp * 8;
                // h1b swizzle keyed to absolute t: (t_base+tr-1)&7 = (tr+7)&7
                af[mi] = *reinterpret_cast<const bf16x8*>(&As[tr * 128 + (cl ^ (((tr + 7) & 7) << 3))]);
            }
            #pragma unroll
            for (int ni = 0; ni < 4; ++ni)
                bfr[ni] = *reinterpret_cast<const bf16x8*>(&Bs[(wni * 4 + ni) * 512 + lane * 8]);
            __syncthreads();
            if (j < 11) {
                int jn = j + 1;
                STAGE_B(((jn >> 2) * 8 + h * 4 + (jn & 3)));
            }
            __builtin_amdgcn_s_setprio(1);
            #pragma unroll
            for (int mi = 0; mi < 2; ++mi)
                #pragma unroll
                for (int ni = 0; ni < 4; ++ni)
                    acc[mi][ni] = __builtin_amdgcn_mfma_f32_16x16x32_bf16(af[mi], bfr[ni], acc[mi][ni], 0, 0, 0);
            __builtin_amdgcn_s_setprio(0);
            __syncthreads();
        }
    }

    // ---- epilogue: bias+relu, LN, dot lin_w, relu -> dur[64]
    float bcol[4], gcol[4], becol[4], wcol[4];
    #pragma unroll
    for (int ni = 0; ni < 4; ++ni) {
        int col = wni * 64 + ni * 16 + lr;
        bcol[ni] = bias[col]; gcol[ni] = g[col]; becol[ni] = be[col]; wcol[ni] = lw[col];
    }
    #pragma unroll
    for (int mi = 0; mi < 2; ++mi)
        #pragma unroll
        for (int ni = 0; ni < 4; ++ni)
            #pragma unroll
            for (int r = 0; r < 4; ++r)
                acc[mi][ni][r] = fmaxf(acc[mi][ni][r] + bcol[ni], 0.f);

    #pragma unroll
    for (int mi = 0; mi < 2; ++mi)
        #pragma unroll
        for (int r = 0; r < 4; ++r) {
            float s = acc[mi][0][r] + acc[mi][1][r] + acc[mi][2][r] + acc[mi][3][r];
            float q = acc[mi][0][r] * acc[mi][0][r] + acc[mi][1][r] * acc[mi][1][r]
                    + acc[mi][2][r] * acc[mi][2][r] + acc[mi][3][r] * acc[mi][3][r];
            #pragma unroll
            for (int off = 1; off < 16; off <<= 1) {
                s += __shfl_xor(s, off);
                q += __shfl_xor(q, off);
            }
            if (lr == 0) {
                int R = wmi * 32 + mi * 16 + grp * 4 + r;
                lnS[wni][R] = s; lnQ[wni][R] = q;
            }
        }
    __syncthreads();
    #pragma unroll
    for (int mi = 0; mi < 2; ++mi)
        #pragma unroll
        for (int r = 0; r < 4; ++r) {
            int R = wmi * 32 + mi * 16 + grp * 4 + r;
            float mu = (lnS[0][R] + lnS[1][R] + lnS[2][R] + lnS[3][R]) * (1.f / 256.f);
            float var = (lnQ[0][R] + lnQ[1][R] + lnQ[2][R] + lnQ[3][R]) * (1.f / 256.f) - mu * mu;
            float rs = rsqrtf(var + 1e-5f);
            float d = ((acc[mi][0][r] - mu) * rs * gcol[0] + becol[0]) * wcol[0]
                    + ((acc[mi][1][r] - mu) * rs * gcol[1] + becol[1]) * wcol[1]
                    + ((acc[mi][2][r] - mu) * rs * gcol[2] + becol[2]) * wcol[2]
                    + ((acc[mi][3][r] - mu) * rs * gcol[3] + becol[3]) * wcol[3];
            #pragma unroll
            for (int off = 1; off < 16; off <<= 1) d += __shfl_xor(d, off);
            if (lr == 0) lnD[wni][R] = d;
        }
    __syncthreads();
    if (tid < 64) {
        float dd = lnD[0][tid] + lnD[1][tid] + lnD[2][tid] + lnD[3][tid] + lb[0];
        dur[(size_t)b * 512 + t_base + tid] = fmaxf(dd, 0.f);
    }
    #undef STAGE_B
}

extern "C" void kernel_launch(void* const* d_in, const int* in_sizes, int n_in,
                              void* d_out, int out_size, void* d_ws, size_t ws_size,
                              hipStream_t stream) {
    const float* x   = (const float*)d_in[0];
    const float* w1  = (const float*)d_in[1];
    const float* b1  = (const float*)d_in[2];
    const float* g1  = (const float*)d_in[3];
    const float* be1 = (const float*)d_in[4];
    const float* w2  = (const float*)d_in[5];
    const float* b2  = (const float*)d_in[6];
    const float* g2  = (const float*)d_in[7];
    const float* be2 = (const float*)d_in[8];
    const float* lw  = (const float*)d_in[9];
    const float* lb  = (const float*)d_in[10];
    const int* tgt   = (const int*)d_in[11];
    float* out = (float*)d_out;

    const int B = 32, T = 512, C = 256;
    const int rows = B * T;                       // 16384
    const int M = (out_size - rows) / (B * C);    // 3584

    char* ws = (char*)d_ws;
    unsigned short* w1p = (unsigned short*)(ws);              //   393,216 B
    unsigned short* w2p = (unsigned short*)(ws + 393216);     //   393,216 B
    unsigned short* h1b = (unsigned short*)(ws + 786432);     // 8,388,608 B
    short* idxT         = (short*)(ws + 9175040);             //   229,376 B

    prep<<<288, 512, 0, stream>>>(w1, w2, w1p, w2p, tgt, idxT, M);
    // grid = 256 conv blocks + 32 batches * 56 gather blocks = 2048
    conv1_hetero<<<2048, 512, 0, stream>>>(x, w1p, b1, g1, be1, h1b, idxT, out, M);
    conv2_hetero<<<2048, 512, 0, stream>>>(h1b, w2p, b2, g2, be2, lw, lb,
                                           out + (size_t)B * M * C, idxT, x, out, M);
}

// Round 12
// 57.970 us; speedup vs baseline: 5.3625x; 1.7127x over previous
//
#include <hip/hip_runtime.h>
#include <hip/hip_bf16.h>

typedef float f32x4 __attribute__((ext_vector_type(4)));
typedef __bf16 bf16x8 __attribute__((ext_vector_type(8)));

static __device__ __forceinline__ unsigned short f2bf(float f) {
    unsigned int u = __float_as_uint(f);
    unsigned int r = (u + 0x7fffu + ((u >> 16) & 1u)) >> 16;   // RNE
    return (unsigned short)r;
}

// async global->LDS, 16B per lane; LDS dest = wave-uniform base + lane*16
static __device__ __forceinline__ void gll16(const void* g, void* l) {
    __builtin_amdgcn_global_load_lds(
        (const __attribute__((address_space(1))) unsigned int*)g,
        (__attribute__((address_space(3))) unsigned int*)l, 16, 0, 0);
}

// ---------------------------------------------------------------------------
// prep: pack conv weights (tile-major MFMA-ready; same layout as rounds 6-10,
// coalesced reads) + cumsum + idx-expand.
// ---------------------------------------------------------------------------
__global__ __launch_bounds__(512) void prep(
    const float* __restrict__ w1, const float* __restrict__ w2,
    unsigned short* __restrict__ w1p, unsigned short* __restrict__ w2p,
    const int* __restrict__ tgt, short* __restrict__ idxT, int M)
{
    int blk = blockIdx.x;
    if (blk < 256) {
        int gi = blk * 512 + threadIdx.x;            // pair index (n,cin)
        const float* w = (gi < 65536) ? w1 : w2;
        unsigned short* wp = (gi < 65536) ? w1p : w2p;
        int p = gi & 65535;
        int n = p >> 8, cin = p & 255;
        const float* src = w + (size_t)p * 3;
        float a[3] = {src[0], src[1], src[2]};
        int nb = n >> 4, nl = n & 15;
        int e = cin & 7, lhi = (cin >> 3) & 3, chi = cin >> 5;
        int base = nb * 512 + (lhi * 16 + nl) * 8 + e;
        #pragma unroll
        for (int kk = 0; kk < 3; ++kk)
            wp[(kk * 8 + chi) * 8192 + base] = f2bf(a[kk]);
    } else {
        __shared__ int s[512];
        int b = blk - 256, tid = threadIdx.x;
        int d = tgt[b * 512 + tid];
        s[tid] = d;
        __syncthreads();
        for (int off = 1; off < 512; off <<= 1) {
            int v = (tid >= off) ? s[tid - off] : 0;
            __syncthreads();
            s[tid] += v;
            __syncthreads();
        }
        int myend = s[tid];          // inclusive cumsum
        int mystart = myend - d;
        short* row = idxT + (size_t)b * M;
        for (int p = mystart; p < myend; ++p) row[p] = (short)tid;
        __syncthreads();
        int total = s[511];
        for (int p = total + tid; p < M; p += 512) row[p] = (short)-1;
    }
}

// ---------------------------------------------------------------------------
// gather part: 32 mel rows / block, 8 waves; idx lookup, plain stores.
// jpb/base are compile-time at each call site.
// ---------------------------------------------------------------------------
static __device__ __forceinline__ void gather_part(
    int gblk, int jpb, int base, const float* __restrict__ x,
    const short* __restrict__ idxT, float* __restrict__ out, int M,
    int wv, int lane)
{
    int b = gblk / jpb;
    int r0 = (gblk - b * jpb) * 32 + base;
    const short* row = idxT + (size_t)b * M;
    int id[4];
    #pragma unroll
    for (int i = 0; i < 4; ++i) id[i] = row[r0 + i * 8 + wv];
    #pragma unroll
    for (int i = 0; i < 4; ++i) {
        int m = r0 + i * 8 + wv;
        float4 v = make_float4(0.f, 0.f, 0.f, 0.f);
        if (id[i] >= 0)
            v = *reinterpret_cast<const float4*>(x + ((size_t)(b * 512 + id[i])) * 256 + lane * 4);
        *reinterpret_cast<float4*>(out + ((size_t)b * M + m) * 256 + lane * 4) = v;
    }
}

// ---------------------------------------------------------------------------
// conv1 + gather rows [0, 2176). BM=64, BN=256, BK=32 (24 tiles), 8 waves.
// Double-buffered B staging (round-6 verified structure).
// ---------------------------------------------------------------------------
__global__ __launch_bounds__(512, 4) void conv1_hetero(
    const float* __restrict__ x, const unsigned short* __restrict__ Wp,
    const float* __restrict__ bias, const float* __restrict__ g,
    const float* __restrict__ be, unsigned short* __restrict__ h1b,
    const short* __restrict__ idxT, float* __restrict__ out, int M)
{
    __shared__ __align__(16) unsigned short As[66 * 256];
    __shared__ __align__(16) unsigned short Bsm[2][8192];
    __shared__ float lnS[4][64], lnQ[4][64];

    const int tid = threadIdx.x;
    const int lane = tid & 63;
    const int wv = tid >> 6;

    if (blockIdx.x >= 256) {
        gather_part(blockIdx.x - 256, 68, 0, x, idxT, out, M, wv, lane);
        return;
    }

    const int wmi = wv >> 2, wni = wv & 3;
    const int grp = lane >> 4, lr = lane & 15;
    const int b = blockIdx.x >> 3;
    const int t_base = (blockIdx.x & 7) * 64;

    // ---- A stage: x rows t_base-1 .. t_base+64 -> bf16, XOR-swizzled (row&7)<<3
    #pragma unroll
    for (int i = 0; i < 9; ++i) {
        int cc = i * 512 + tid;
        if (cc < 66 * 64) {
            int row = cc >> 6, q = cc & 63;
            int tt = t_base - 1 + row;
            ushort4 o = make_ushort4(0, 0, 0, 0);
            if ((unsigned)tt < 512u) {
                float4 v = *reinterpret_cast<const float4*>(x + ((size_t)(b * 512 + tt)) * 256 + q * 4);
                o.x = f2bf(v.x); o.y = f2bf(v.y); o.z = f2bf(v.z); o.w = f2bf(v.w);
            }
            *reinterpret_cast<ushort4*>(&As[row * 256 + ((q * 4) ^ ((row & 7) << 3))]) = o;
        }
    }

    // ---- B double-buffered pipeline via global_load_lds
    const char* wpB = (const char*)Wp;
    char* bs0 = (char*)&Bsm[0][0];
    #define STAGE_B(kt, buf) do {                                              \
        const char* _s = wpB + (kt) * 16384 + wv * 2048 + lane * 16;           \
        char* _d = bs0 + (buf) * 16384 + wv * 2048;                            \
        gll16(_s, _d); gll16(_s + 1024, _d + 1024);                            \
    } while (0)

    STAGE_B(0, 0);
    __syncthreads();

    f32x4 acc[2][4] = {};
    int cur = 0;
    for (int kt = 0; kt < 24; ++kt) {
        if (kt < 23) STAGE_B(kt + 1, cur ^ 1);
        const int kk = kt >> 3, cin0 = (kt & 7) * 32;
        bf16x8 af[2], bfr[4];
        #pragma unroll
        for (int mi = 0; mi < 2; ++mi) {
            int tr = wmi * 32 + mi * 16 + lr + kk;
            af[mi] = *reinterpret_cast<const bf16x8*>(&As[tr * 256 + ((cin0 + grp * 8) ^ ((tr & 7) << 3))]);
        }
        #pragma unroll
        for (int ni = 0; ni < 4; ++ni)
            bfr[ni] = *reinterpret_cast<const bf16x8*>(&Bsm[cur][(wni * 4 + ni) * 512 + lane * 8]);
        __builtin_amdgcn_s_setprio(1);
        #pragma unroll
        for (int mi = 0; mi < 2; ++mi)
            #pragma unroll
            for (int ni = 0; ni < 4; ++ni)
                acc[mi][ni] = __builtin_amdgcn_mfma_f32_16x16x32_bf16(af[mi], bfr[ni], acc[mi][ni], 0, 0, 0);
        __builtin_amdgcn_s_setprio(0);
        __syncthreads();
        cur ^= 1;
    }

    // ---- epilogue: bias+relu, LN, LDS-staged vectorized bf16 store
    float bcol[4], gcol[4], becol[4];
    #pragma unroll
    for (int ni = 0; ni < 4; ++ni) {
        int col = wni * 64 + ni * 16 + lr;
        bcol[ni] = bias[col]; gcol[ni] = g[col]; becol[ni] = be[col];
    }
    #pragma unroll
    for (int mi = 0; mi < 2; ++mi)
        #pragma unroll
        for (int ni = 0; ni < 4; ++ni)
            #pragma unroll
            for (int r = 0; r < 4; ++r)
                acc[mi][ni][r] = fmaxf(acc[mi][ni][r] + bcol[ni], 0.f);

    #pragma unroll
    for (int mi = 0; mi < 2; ++mi)
        #pragma unroll
        for (int r = 0; r < 4; ++r) {
            float s = acc[mi][0][r] + acc[mi][1][r] + acc[mi][2][r] + acc[mi][3][r];
            float q = acc[mi][0][r] * acc[mi][0][r] + acc[mi][1][r] * acc[mi][1][r]
                    + acc[mi][2][r] * acc[mi][2][r] + acc[mi][3][r] * acc[mi][3][r];
            #pragma unroll
            for (int off = 1; off < 16; off <<= 1) {
                s += __shfl_xor(s, off);
                q += __shfl_xor(q, off);
            }
            if (lr == 0) {
                int R = wmi * 32 + mi * 16 + grp * 4 + r;
                lnS[wni][R] = s; lnQ[wni][R] = q;
            }
        }
    __syncthreads();

    unsigned short* Hs = &Bsm[0][0];   // 32 KB, dead after K-loop
    #pragma unroll
    for (int mi = 0; mi < 2; ++mi)
        #pragma unroll
        for (int r = 0; r < 4; ++r) {
            int R = wmi * 32 + mi * 16 + grp * 4 + r;
            float mu = (lnS[0][R] + lnS[1][R] + lnS[2][R] + lnS[3][R]) * (1.f / 256.f);
            float var = (lnQ[0][R] + lnQ[1][R] + lnQ[2][R] + lnQ[3][R]) * (1.f / 256.f) - mu * mu;
            float rs = rsqrtf(var + 1e-5f);
            #pragma unroll
            for (int ni = 0; ni < 4; ++ni) {
                int col = wni * 64 + ni * 16 + lr;
                float h = (acc[mi][ni][r] - mu) * rs * gcol[ni] + becol[ni];
                Hs[R * 256 + (col ^ ((R & 7) << 3))] = f2bf(h);   // conv2's swizzle
            }
        }
    __syncthreads();
    // linear copy preserves the baked-in swizzle; fully coalesced 16B stores
    #pragma unroll
    for (int i = 0; i < 4; ++i) {
        int c = i * 512 + tid;          // 2048 chunks of 16B
        int row = c >> 5, seg = c & 31;
        uint4 v = *reinterpret_cast<const uint4*>(&Hs[row * 256 + seg * 8]);
        *reinterpret_cast<uint4*>(h1b + ((size_t)(b * 512 + t_base + row)) * 256 + seg * 8) = v;
    }
    #undef STAGE_B
}

// ---------------------------------------------------------------------------
// conv2 + LN + linear + relu -> dur, + gather rows [2176, 3584)
// ---------------------------------------------------------------------------
__global__ __launch_bounds__(512, 4) void conv2_hetero(
    const unsigned short* __restrict__ h1b, const unsigned short* __restrict__ Wp,
    const float* __restrict__ bias, const float* __restrict__ g,
    const float* __restrict__ be, const float* __restrict__ lw,
    const float* __restrict__ lb, float* __restrict__ dur,
    const short* __restrict__ idxT, const float* __restrict__ x,
    float* __restrict__ out, int M)
{
    __shared__ __align__(16) unsigned short As[66 * 256];
    __shared__ __align__(16) unsigned short Bsm[2][8192];
    __shared__ float lnS[4][64], lnQ[4][64], lnD[4][64];

    const int tid = threadIdx.x;
    const int lane = tid & 63;
    const int wv = tid >> 6;

    if (blockIdx.x >= 256) {
        gather_part(blockIdx.x - 256, 44, 2176, x, idxT, out, M, wv, lane);
        return;
    }

    const int wmi = wv >> 2, wni = wv & 3;
    const int grp = lane >> 4, lr = lane & 15;
    const int b = blockIdx.x >> 3;
    const int t_base = (blockIdx.x & 7) * 64;

    // ---- A stage: interior rows 1..64 via global_load_lds (h1b is pre-swizzled)
    {
        const char* src = (const char*)h1b + ((size_t)(b * 512 + t_base)) * 512 + wv * 4096 + lane * 16;
        char* dst = (char*)&As[256] + wv * 4096;
        #pragma unroll
        for (int i = 0; i < 4; ++i) gll16(src + i * 1024, dst + i * 1024);
    }
    // halo rows 0 (t_base-1) and 65 (t_base+64), zero-padded
    if (tid < 32) {
        int tt = t_base - 1;
        uint4 v = make_uint4(0u, 0u, 0u, 0u);
        if (tt >= 0)
            v = *reinterpret_cast<const uint4*>((const char*)h1b + ((size_t)(b * 512 + tt)) * 512 + tid * 16);
        *reinterpret_cast<uint4*>((char*)As + tid * 16) = v;
    } else if (tid < 64) {
        int t2 = tid - 32, tt = t_base + 64;
        uint4 v = make_uint4(0u, 0u, 0u, 0u);
        if (tt < 512)
            v = *reinterpret_cast<const uint4*>((const char*)h1b + ((size_t)(b * 512 + tt)) * 512 + t2 * 16);
        *reinterpret_cast<uint4*>((char*)&As[65 * 256] + t2 * 16) = v;
    }

    const char* wpB = (const char*)Wp;
    char* bs0 = (char*)&Bsm[0][0];
    #define STAGE_B(kt, buf) do {                                              \
        const char* _s = wpB + (kt) * 16384 + wv * 2048 + lane * 16;           \
        char* _d = bs0 + (buf) * 16384 + wv * 2048;                            \
        gll16(_s, _d); gll16(_s + 1024, _d + 1024);                            \
    } while (0)

    STAGE_B(0, 0);
    __syncthreads();

    f32x4 acc[2][4] = {};
    int cur = 0;
    for (int kt = 0; kt < 24; ++kt) {
        if (kt < 23) STAGE_B(kt + 1, cur ^ 1);
        const int kk = kt >> 3, cin0 = (kt & 7) * 32;
        bf16x8 af[2], bfr[4];
        #pragma unroll
        for (int mi = 0; mi < 2; ++mi) {
            int tr = wmi * 32 + mi * 16 + lr + kk;
            // h1b swizzle follows absolute t = t_base + tr - 1 -> bits (tr+7)&7
            af[mi] = *reinterpret_cast<const bf16x8*>(&As[tr * 256 + ((cin0 + grp * 8) ^ (((tr + 7) & 7) << 3))]);
        }
        #pragma unroll
        for (int ni = 0; ni < 4; ++ni)
            bfr[ni] = *reinterpret_cast<const bf16x8*>(&Bsm[cur][(wni * 4 + ni) * 512 + lane * 8]);
        __builtin_amdgcn_s_setprio(1);
        #pragma unroll
        for (int mi = 0; mi < 2; ++mi)
            #pragma unroll
            for (int ni = 0; ni < 4; ++ni)
                acc[mi][ni] = __builtin_amdgcn_mfma_f32_16x16x32_bf16(af[mi], bfr[ni], acc[mi][ni], 0, 0, 0);
        __builtin_amdgcn_s_setprio(0);
        __syncthreads();
        cur ^= 1;
    }

    // ---- epilogue: bias+relu, LN, dot lin_w, relu -> dur[64]
    float bcol[4], gcol[4], becol[4], wcol[4];
    #pragma unroll
    for (int ni = 0; ni < 4; ++ni) {
        int col = wni * 64 + ni * 16 + lr;
        bcol[ni] = bias[col]; gcol[ni] = g[col]; becol[ni] = be[col]; wcol[ni] = lw[col];
    }
    #pragma unroll
    for (int mi = 0; mi < 2; ++mi)
        #pragma unroll
        for (int ni = 0; ni < 4; ++ni)
            #pragma unroll
            for (int r = 0; r < 4; ++r)
                acc[mi][ni][r] = fmaxf(acc[mi][ni][r] + bcol[ni], 0.f);

    #pragma unroll
    for (int mi = 0; mi < 2; ++mi)
        #pragma unroll
        for (int r = 0; r < 4; ++r) {
            float s = acc[mi][0][r] + acc[mi][1][r] + acc[mi][2][r] + acc[mi][3][r];
            float q = acc[mi][0][r] * acc[mi][0][r] + acc[mi][1][r] * acc[mi][1][r]
                    + acc[mi][2][r] * acc[mi][2][r] + acc[mi][3][r] * acc[mi][3][r];
            #pragma unroll
            for (int off = 1; off < 16; off <<= 1) {
                s += __shfl_xor(s, off);
                q += __shfl_xor(q, off);
            }
            if (lr == 0) {
                int R = wmi * 32 + mi * 16 + grp * 4 + r;
                lnS[wni][R] = s; lnQ[wni][R] = q;
            }
        }
    __syncthreads();
    #pragma unroll
    for (int mi = 0; mi < 2; ++mi)
        #pragma unroll
        for (int r = 0; r < 4; ++r) {
            int R = wmi * 32 + mi * 16 + grp * 4 + r;
            float mu = (lnS[0][R] + lnS[1][R] + lnS[2][R] + lnS[3][R]) * (1.f / 256.f);
            float var = (lnQ[0][R] + lnQ[1][R] + lnQ[2][R] + lnQ[3][R]) * (1.f / 256.f) - mu * mu;
            float rs = rsqrtf(var + 1e-5f);
            float d = ((acc[mi][0][r] - mu) * rs * gcol[0] + becol[0]) * wcol[0]
                    + ((acc[mi][1][r] - mu) * rs * gcol[1] + becol[1]) * wcol[1]
                    + ((acc[mi][2][r] - mu) * rs * gcol[2] + becol[2]) * wcol[2]
                    + ((acc[mi][3][r] - mu) * rs * gcol[3] + becol[3]) * wcol[3];
            #pragma unroll
            for (int off = 1; off < 16; off <<= 1) d += __shfl_xor(d, off);
            if (lr == 0) lnD[wni][R] = d;
        }
    __syncthreads();
    if (tid < 64) {
        float dd = lnD[0][tid] + lnD[1][tid] + lnD[2][tid] + lnD[3][tid] + lb[0];
        dur[(size_t)b * 512 + t_base + tid] = fmaxf(dd, 0.f);
    }
    #undef STAGE_B
}

extern "C" void kernel_launch(void* const* d_in, const int* in_sizes, int n_in,
                              void* d_out, int out_size, void* d_ws, size_t ws_size,
                              hipStream_t stream) {
    const float* x   = (const float*)d_in[0];
    const float* w1  = (const float*)d_in[1];
    const float* b1  = (const float*)d_in[2];
    const float* g1  = (const float*)d_in[3];
    const float* be1 = (const float*)d_in[4];
    const float* w2  = (const float*)d_in[5];
    const float* b2  = (const float*)d_in[6];
    const float* g2  = (const float*)d_in[7];
    const float* be2 = (const float*)d_in[8];
    const float* lw  = (const float*)d_in[9];
    const float* lb  = (const float*)d_in[10];
    const int* tgt   = (const int*)d_in[11];
    float* out = (float*)d_out;

    const int B = 32, T = 512, C = 256;
    const int rows = B * T;                       // 16384
    const int M = (out_size - rows) / (B * C);    // 3584

    char* ws = (char*)d_ws;
    unsigned short* w1p = (unsigned short*)(ws);              //   393,216 B
    unsigned short* w2p = (unsigned short*)(ws + 393216);     //   393,216 B
    unsigned short* h1b = (unsigned short*)(ws + 786432);     // 8,388,608 B
    short* idxT         = (short*)(ws + 9175040);             //   229,376 B

    prep<<<288, 512, 0, stream>>>(w1, w2, w1p, w2p, tgt, idxT, M);
    // K1: 256 conv blocks + 32 batches * 68 gather blocks (rows [0,2176))
    conv1_hetero<<<2432, 512, 0, stream>>>(x, w1p, b1, g1, be1, h1b, idxT, out, M);
    // K2: 256 conv blocks + 32 batches * 44 gather blocks (rows [2176,3584))
    conv2_hetero<<<1664, 512, 0, stream>>>(h1b, w2p, b2, g2, be2, lw, lb,
                                           out + (size_t)B * M * C, idxT, x, out, M);
}

// Round 13
// 57.874 us; speedup vs baseline: 5.3714x; 1.0017x over previous
//
#include <hip/hip_runtime.h>
#include <hip/hip_bf16.h>

typedef float f32x4 __attribute__((ext_vector_type(4)));
typedef __bf16 bf16x8 __attribute__((ext_vector_type(8)));

static __device__ __forceinline__ unsigned short f2bf(float f) {
    unsigned int u = __float_as_uint(f);
    unsigned int r = (u + 0x7fffu + ((u >> 16) & 1u)) >> 16;   // RNE
    return (unsigned short)r;
}

// async global->LDS, 16B per lane; LDS dest = wave-uniform base + lane*16,
// global src is per-lane.
static __device__ __forceinline__ void gll16(const void* g, void* l) {
    __builtin_amdgcn_global_load_lds(
        (const __attribute__((address_space(1))) unsigned int*)g,
        (__attribute__((address_space(3))) unsigned int*)l, 16, 0, 0);
}

// ---------------------------------------------------------------------------
// prep: pack conv weights (tile-major MFMA-ready, coalesced reads) +
// cumsum + idx-expand.  (unchanged from round 12)
// ---------------------------------------------------------------------------
__global__ __launch_bounds__(512) void prep(
    const float* __restrict__ w1, const float* __restrict__ w2,
    unsigned short* __restrict__ w1p, unsigned short* __restrict__ w2p,
    const int* __restrict__ tgt, short* __restrict__ idxT, int M)
{
    int blk = blockIdx.x;
    if (blk < 256) {
        int gi = blk * 512 + threadIdx.x;            // pair index (n,cin)
        const float* w = (gi < 65536) ? w1 : w2;
        unsigned short* wp = (gi < 65536) ? w1p : w2p;
        int p = gi & 65535;
        int n = p >> 8, cin = p & 255;
        const float* src = w + (size_t)p * 3;
        float a[3] = {src[0], src[1], src[2]};
        int nb = n >> 4, nl = n & 15;
        int e = cin & 7, lhi = (cin >> 3) & 3, chi = cin >> 5;
        int base = nb * 512 + (lhi * 16 + nl) * 8 + e;
        #pragma unroll
        for (int kk = 0; kk < 3; ++kk)
            wp[(kk * 8 + chi) * 8192 + base] = f2bf(a[kk]);
    } else {
        __shared__ int s[512];
        int b = blk - 256, tid = threadIdx.x;
        int d = tgt[b * 512 + tid];
        s[tid] = d;
        __syncthreads();
        for (int off = 1; off < 512; off <<= 1) {
            int v = (tid >= off) ? s[tid - off] : 0;
            __syncthreads();
            s[tid] += v;
            __syncthreads();
        }
        int myend = s[tid];          // inclusive cumsum
        int mystart = myend - d;
        short* row = idxT + (size_t)b * M;
        for (int p = mystart; p < myend; ++p) row[p] = (short)tid;
        __syncthreads();
        int total = s[511];
        for (int p = total + tid; p < M; p += 512) row[p] = (short)-1;
    }
}

// ---------------------------------------------------------------------------
// gather part: 32 mel rows / block, 8 waves; idx lookup, plain stores
// ---------------------------------------------------------------------------
static __device__ __forceinline__ void gather_part(
    int gblk, int jpb, int base, const float* __restrict__ x,
    const short* __restrict__ idxT, float* __restrict__ out, int M,
    int wv, int lane)
{
    int b = gblk / jpb;
    int r0 = (gblk - b * jpb) * 32 + base;
    const short* row = idxT + (size_t)b * M;
    int id[4];
    #pragma unroll
    for (int i = 0; i < 4; ++i) id[i] = row[r0 + i * 8 + wv];
    #pragma unroll
    for (int i = 0; i < 4; ++i) {
        int m = r0 + i * 8 + wv;
        float4 v = make_float4(0.f, 0.f, 0.f, 0.f);
        if (id[i] >= 0)
            v = *reinterpret_cast<const float4*>(x + ((size_t)(b * 512 + id[i])) * 256 + lane * 4);
        *reinterpret_cast<float4*>(out + ((size_t)b * M + m) * 256 + lane * 4) = v;
    }
}

// ---------------------------------------------------------------------------
// conv1 + gather rows [0,2176). BM=64, BN=256; K as 2 cin-halves x 12 BK=32
// tiles; double-buffered B.  LDS: As[66][128] 16.9K + Bsm 32K + ln 2K = 51.7K
// -> 3 blocks/CU at 64 VGPR.
// ---------------------------------------------------------------------------
__global__ __launch_bounds__(512, 4) void conv1_hetero(
    const float* __restrict__ x, const unsigned short* __restrict__ Wp,
    const float* __restrict__ bias, const float* __restrict__ g,
    const float* __restrict__ be, unsigned short* __restrict__ h1b,
    const short* __restrict__ idxT, float* __restrict__ out, int M)
{
    __shared__ __align__(16) unsigned short As[66 * 128];
    __shared__ __align__(16) unsigned short Bsm[2][8192];
    __shared__ float lnS[4][64], lnQ[4][64];

    const int tid = threadIdx.x;
    const int lane = tid & 63;
    const int wv = tid >> 6;

    if (blockIdx.x >= 256) {
        gather_part(blockIdx.x - 256, 68, 0, x, idxT, out, M, wv, lane);
        return;
    }

    const int wmi = wv >> 2, wni = wv & 3;
    const int grp = lane >> 4, lr = lane & 15;
    const int b = blockIdx.x >> 3;
    const int t_base = (blockIdx.x & 7) * 64;

    const char* wpB = (const char*)Wp;
    char* bs0 = (char*)&Bsm[0][0];
    #define STAGE_B(ktg, buf) do {                                             \
        const char* _s = wpB + (ktg) * 16384 + wv * 2048 + lane * 16;          \
        char* _d = bs0 + (buf) * 16384 + wv * 2048;                            \
        gll16(_s, _d); gll16(_s + 1024, _d + 1024);                            \
    } while (0)

    f32x4 acc[2][4] = {};
    int cur = 0;

    for (int h = 0; h < 2; ++h) {
        // ---- A-stage: rows t_base-1..t_base+64, cin [h*128, h*128+128)
        #pragma unroll
        for (int i = 0; i < 5; ++i) {
            int cc = i * 512 + tid;                 // 2112 ushort4 chunks
            if (cc < 66 * 32) {
                int row = cc >> 5, ql = cc & 31;
                int tt = t_base - 1 + row;
                ushort4 o = make_ushort4(0, 0, 0, 0);
                if ((unsigned)tt < 512u) {
                    float4 v = *reinterpret_cast<const float4*>(
                        x + ((size_t)(b * 512 + tt)) * 256 + h * 128 + ql * 4);
                    o.x = f2bf(v.x); o.y = f2bf(v.y); o.z = f2bf(v.z); o.w = f2bf(v.w);
                }
                *reinterpret_cast<ushort4*>(&As[row * 128 + ((ql * 4) ^ ((row & 7) << 3))]) = o;
            }
        }
        STAGE_B(h * 4, cur);                        // first tile of this half
        __syncthreads();

        for (int j = 0; j < 12; ++j) {
            if (j < 11) {
                int jn = j + 1;
                STAGE_B((jn >> 2) * 8 + h * 4 + (jn & 3), cur ^ 1);
            }
            const int cbl = j & 3, kk = j >> 2;
            bf16x8 af[2], bfr[4];
            #pragma unroll
            for (int mi = 0; mi < 2; ++mi) {
                int tr = wmi * 32 + mi * 16 + lr + kk;
                af[mi] = *reinterpret_cast<const bf16x8*>(
                    &As[tr * 128 + ((cbl * 32 + grp * 8) ^ ((tr & 7) << 3))]);
            }
            #pragma unroll
            for (int ni = 0; ni < 4; ++ni)
                bfr[ni] = *reinterpret_cast<const bf16x8*>(&Bsm[cur][(wni * 4 + ni) * 512 + lane * 8]);
            __builtin_amdgcn_s_setprio(1);
            #pragma unroll
            for (int mi = 0; mi < 2; ++mi)
                #pragma unroll
                for (int ni = 0; ni < 4; ++ni)
                    acc[mi][ni] = __builtin_amdgcn_mfma_f32_16x16x32_bf16(af[mi], bfr[ni], acc[mi][ni], 0, 0, 0);
            __builtin_amdgcn_s_setprio(0);
            __syncthreads();
            cur ^= 1;
        }
    }

    // ---- epilogue: bias+relu, LN, LDS-staged (Bsm arena, 32KB) bf16 store
    float bcol[4], gcol[4], becol[4];
    #pragma unroll
    for (int ni = 0; ni < 4; ++ni) {
        int col = wni * 64 + ni * 16 + lr;
        bcol[ni] = bias[col]; gcol[ni] = g[col]; becol[ni] = be[col];
    }
    #pragma unroll
    for (int mi = 0; mi < 2; ++mi)
        #pragma unroll
        for (int ni = 0; ni < 4; ++ni)
            #pragma unroll
            for (int r = 0; r < 4; ++r)
                acc[mi][ni][r] = fmaxf(acc[mi][ni][r] + bcol[ni], 0.f);

    #pragma unroll
    for (int mi = 0; mi < 2; ++mi)
        #pragma unroll
        for (int r = 0; r < 4; ++r) {
            float s = acc[mi][0][r] + acc[mi][1][r] + acc[mi][2][r] + acc[mi][3][r];
            float q = acc[mi][0][r] * acc[mi][0][r] + acc[mi][1][r] * acc[mi][1][r]
                    + acc[mi][2][r] * acc[mi][2][r] + acc[mi][3][r] * acc[mi][3][r];
            #pragma unroll
            for (int off = 1; off < 16; off <<= 1) {
                s += __shfl_xor(s, off);
                q += __shfl_xor(q, off);
            }
            if (lr == 0) {
                int R = wmi * 32 + mi * 16 + grp * 4 + r;
                lnS[wni][R] = s; lnQ[wni][R] = q;
            }
        }
    __syncthreads();

    unsigned short* Hs = &Bsm[0][0];   // 32 KB exactly
    #pragma unroll
    for (int mi = 0; mi < 2; ++mi)
        #pragma unroll
        for (int r = 0; r < 4; ++r) {
            int R = wmi * 32 + mi * 16 + grp * 4 + r;
            float mu = (lnS[0][R] + lnS[1][R] + lnS[2][R] + lnS[3][R]) * (1.f / 256.f);
            float var = (lnQ[0][R] + lnQ[1][R] + lnQ[2][R] + lnQ[3][R]) * (1.f / 256.f) - mu * mu;
            float rs = rsqrtf(var + 1e-5f);
            #pragma unroll
            for (int ni = 0; ni < 4; ++ni) {
                int col = wni * 64 + ni * 16 + lr;
                float hv = (acc[mi][ni][r] - mu) * rs * gcol[ni] + becol[ni];
                Hs[R * 256 + (col ^ ((R & 7) << 3))] = f2bf(hv);   // conv2's swizzle
            }
        }
    __syncthreads();
    #pragma unroll
    for (int i = 0; i < 4; ++i) {
        int c = i * 512 + tid;          // 2048 chunks of 16B, coalesced
        int row = c >> 5, seg = c & 31;
        uint4 v = *reinterpret_cast<const uint4*>(&Hs[row * 256 + seg * 8]);
        *reinterpret_cast<uint4*>(h1b + ((size_t)(b * 512 + t_base + row)) * 256 + seg * 8) = v;
    }
    #undef STAGE_B
}

// ---------------------------------------------------------------------------
// conv2 + LN + linear + relu -> dur, + gather rows [2176,3584)
// ---------------------------------------------------------------------------
__global__ __launch_bounds__(512, 4) void conv2_hetero(
    const unsigned short* __restrict__ h1b, const unsigned short* __restrict__ Wp,
    const float* __restrict__ bias, const float* __restrict__ g,
    const float* __restrict__ be, const float* __restrict__ lw,
    const float* __restrict__ lb, float* __restrict__ dur,
    const short* __restrict__ idxT, const float* __restrict__ x,
    float* __restrict__ out, int M)
{
    __shared__ __align__(16) unsigned short As[66 * 128];
    __shared__ __align__(16) unsigned short Bsm[2][8192];
    __shared__ float lnS[4][64], lnQ[4][64], lnD[4][64];

    const int tid = threadIdx.x;
    const int lane = tid & 63;
    const int wv = tid >> 6;

    if (blockIdx.x >= 256) {
        gather_part(blockIdx.x - 256, 44, 2176, x, idxT, out, M, wv, lane);
        return;
    }

    const int wmi = wv >> 2, wni = wv & 3;
    const int grp = lane >> 4, lr = lane & 15;
    const int b = blockIdx.x >> 3;
    const int t_base = (blockIdx.x & 7) * 64;

    const char* wpB = (const char*)Wp;
    const char* h1B = (const char*)h1b;
    char* bs0 = (char*)&Bsm[0][0];
    #define STAGE_B(ktg, buf) do {                                             \
        const char* _s = wpB + (ktg) * 16384 + wv * 2048 + lane * 16;          \
        char* _d = bs0 + (buf) * 16384 + wv * 2048;                            \
        gll16(_s, _d); gll16(_s + 1024, _d + 1024);                            \
    } while (0)

    f32x4 acc[2][4] = {};
    int cur = 0;

    for (int h = 0; h < 2; ++h) {
        // ---- A-stage: interior rows 1..64, half h via per-lane-src gll16
        // (h1b is pre-swizzled; each 128-col half is closed under the XOR)
        #pragma unroll
        for (int j2 = 0; j2 < 2; ++j2) {
            int row0 = 1 + wv * 8 + j2 * 4;
            const char* src = h1B
                + ((size_t)(b * 512 + t_base + wv * 8 + j2 * 4 + (lane >> 4))) * 512
                + h * 256 + (lane & 15) * 16;
            gll16(src, (char*)As + row0 * 256);
        }
        // halo rows 0 (t=t_base-1) and 65 (t=t_base+64), 256B each
        if (tid < 16) {
            int tt = t_base - 1;
            uint4 v = make_uint4(0u, 0u, 0u, 0u);
            if (tt >= 0)
                v = *reinterpret_cast<const uint4*>(h1B + ((size_t)(b * 512 + tt)) * 512 + h * 256 + tid * 16);
            *reinterpret_cast<uint4*>((char*)As + tid * 16) = v;
        } else if (tid < 32) {
            int t2 = tid - 16, tt = t_base + 64;
            uint4 v = make_uint4(0u, 0u, 0u, 0u);
            if (tt < 512)
                v = *reinterpret_cast<const uint4*>(h1B + ((size_t)(b * 512 + tt)) * 512 + h * 256 + t2 * 16);
            *reinterpret_cast<uint4*>((char*)As + 65 * 256 + t2 * 16) = v;
        }
        STAGE_B(h * 4, cur);
        __syncthreads();

        for (int j = 0; j < 12; ++j) {
            if (j < 11) {
                int jn = j + 1;
                STAGE_B((jn >> 2) * 8 + h * 4 + (jn & 3), cur ^ 1);
            }
            const int cbl = j & 3, kk = j >> 2;
            bf16x8 af[2], bfr[4];
            #pragma unroll
            for (int mi = 0; mi < 2; ++mi) {
                int tr = wmi * 32 + mi * 16 + lr + kk;
                // swizzle keyed to absolute t: (t_base+tr-1)&7 = (tr+7)&7
                af[mi] = *reinterpret_cast<const bf16x8*>(
                    &As[tr * 128 + ((cbl * 32 + grp * 8) ^ (((tr + 7) & 7) << 3))]);
            }
            #pragma unroll
            for (int ni = 0; ni < 4; ++ni)
                bfr[ni] = *reinterpret_cast<const bf16x8*>(&Bsm[cur][(wni * 4 + ni) * 512 + lane * 8]);
            __builtin_amdgcn_s_setprio(1);
            #pragma unroll
            for (int mi = 0; mi < 2; ++mi)
                #pragma unroll
                for (int ni = 0; ni < 4; ++ni)
                    acc[mi][ni] = __builtin_amdgcn_mfma_f32_16x16x32_bf16(af[mi], bfr[ni], acc[mi][ni], 0, 0, 0);
            __builtin_amdgcn_s_setprio(0);
            __syncthreads();
            cur ^= 1;
        }
    }

    // ---- epilogue: bias+relu, LN, dot lin_w, relu -> dur[64]
    float bcol[4], gcol[4], becol[4], wcol[4];
    #pragma unroll
    for (int ni = 0; ni < 4; ++ni) {
        int col = wni * 64 + ni * 16 + lr;
        bcol[ni] = bias[col]; gcol[ni] = g[col]; becol[ni] = be[col]; wcol[ni] = lw[col];
    }
    #pragma unroll
    for (int mi = 0; mi < 2; ++mi)
        #pragma unroll
        for (int ni = 0; ni < 4; ++ni)
            #pragma unroll
            for (int r = 0; r < 4; ++r)
                acc[mi][ni][r] = fmaxf(acc[mi][ni][r] + bcol[ni], 0.f);

    #pragma unroll
    for (int mi = 0; mi < 2; ++mi)
        #pragma unroll
        for (int r = 0; r < 4; ++r) {
            float s = acc[mi][0][r] + acc[mi][1][r] + acc[mi][2][r] + acc[mi][3][r];
            float q = acc[mi][0][r] * acc[mi][0][r] + acc[mi][1][r] * acc[mi][1][r]
                    + acc[mi][2][r] * acc[mi][2][r] + acc[mi][3][r] * acc[mi][3][r];
            #pragma unroll
            for (int off = 1; off < 16; off <<= 1) {
                s += __shfl_xor(s, off);
                q += __shfl_xor(q, off);
            }
            if (lr == 0) {
                int R = wmi * 32 + mi * 16 + grp * 4 + r;
                lnS[wni][R] = s; lnQ[wni][R] = q;
            }
        }
    __syncthreads();
    #pragma unroll
    for (int mi = 0; mi < 2; ++mi)
        #pragma unroll
        for (int r = 0; r < 4; ++r) {
            int R = wmi * 32 + mi * 16 + grp * 4 + r;
            float mu = (lnS[0][R] + lnS[1][R] + lnS[2][R] + lnS[3][R]) * (1.f / 256.f);
            float var = (lnQ[0][R] + lnQ[1][R] + lnQ[2][R] + lnQ[3][R]) * (1.f / 256.f) - mu * mu;
            float rs = rsqrtf(var + 1e-5f);
            float d = ((acc[mi][0][r] - mu) * rs * gcol[0] + becol[0]) * wcol[0]
                    + ((acc[mi][1][r] - mu) * rs * gcol[1] + becol[1]) * wcol[1]
                    + ((acc[mi][2][r] - mu) * rs * gcol[2] + becol[2]) * wcol[2]
                    + ((acc[mi][3][r] - mu) * rs * gcol[3] + becol[3]) * wcol[3];
            #pragma unroll
            for (int off = 1; off < 16; off <<= 1) d += __shfl_xor(d, off);
            if (lr == 0) lnD[wni][R] = d;
        }
    __syncthreads();
    if (tid < 64) {
        float dd = lnD[0][tid] + lnD[1][tid] + lnD[2][tid] + lnD[3][tid] + lb[0];
        dur[(size_t)b * 512 + t_base + tid] = fmaxf(dd, 0.f);
    }
    #undef STAGE_B
}

extern "C" void kernel_launch(void* const* d_in, const int* in_sizes, int n_in,
                              void* d_out, int out_size, void* d_ws, size_t ws_size,
                              hipStream_t stream) {
    const float* x   = (const float*)d_in[0];
    const float* w1  = (const float*)d_in[1];
    const float* b1  = (const float*)d_in[2];
    const float* g1  = (const float*)d_in[3];
    const float* be1 = (const float*)d_in[4];
    const float* w2  = (const float*)d_in[5];
    const float* b2  = (const float*)d_in[6];
    const float* g2  = (const float*)d_in[7];
    const float* be2 = (const float*)d_in[8];
    const float* lw  = (const float*)d_in[9];
    const float* lb  = (const float*)d_in[10];
    const int* tgt   = (const int*)d_in[11];
    float* out = (float*)d_out;

    const int B = 32, T = 512, C = 256;
    const int rows = B * T;                       // 16384
    const int M = (out_size - rows) / (B * C);    // 3584

    char* ws = (char*)d_ws;
    unsigned short* w1p = (unsigned short*)(ws);              //   393,216 B
    unsigned short* w2p = (unsigned short*)(ws + 393216);     //   393,216 B
    unsigned short* h1b = (unsigned short*)(ws + 786432);     // 8,388,608 B
    short* idxT         = (short*)(ws + 9175040);             //   229,376 B

    prep<<<288, 512, 0, stream>>>(w1, w2, w1p, w2p, tgt, idxT, M);
    // K1: 256 conv blocks + 32 batches * 68 gather blocks (rows [0,2176))
    conv1_hetero<<<2432, 512, 0, stream>>>(x, w1p, b1, g1, be1, h1b, idxT, out, M);
    // K2: 256 conv blocks + 32 batches * 44 gather blocks (rows [2176,3584))
    conv2_hetero<<<1664, 512, 0, stream>>>(h1b, w2p, b2, g2, be2, lw, lb,
                                           out + (size_t)B * M * C, idxT, x, out, M);
}

// Round 14
// 57.750 us; speedup vs baseline: 5.3829x; 1.0021x over previous
//
#include <hip/hip_runtime.h>
#include <hip/hip_bf16.h>

typedef float f32x4 __attribute__((ext_vector_type(4)));
typedef __bf16 bf16x8 __attribute__((ext_vector_type(8)));

static __device__ __forceinline__ unsigned short f2bf(float f) {
    unsigned int u = __float_as_uint(f);
    unsigned int r = (u + 0x7fffu + ((u >> 16) & 1u)) >> 16;   // RNE
    return (unsigned short)r;
}

// async global->LDS, 16B per lane; LDS dest = wave-uniform base + lane*16,
// global src is per-lane.
static __device__ __forceinline__ void gll16(const void* g, void* l) {
    __builtin_amdgcn_global_load_lds(
        (const __attribute__((address_space(1))) unsigned int*)g,
        (__attribute__((address_space(3))) unsigned int*)l, 16, 0, 0);
}

// ---------------------------------------------------------------------------
// prep: pack conv weights (tile-major MFMA-ready, coalesced reads) +
// cumsum + idx-expand.
// ---------------------------------------------------------------------------
__global__ __launch_bounds__(512) void prep(
    const float* __restrict__ w1, const float* __restrict__ w2,
    unsigned short* __restrict__ w1p, unsigned short* __restrict__ w2p,
    const int* __restrict__ tgt, short* __restrict__ idxT, int M)
{
    int blk = blockIdx.x;
    if (blk < 256) {
        int gi = blk * 512 + threadIdx.x;            // pair index (n,cin)
        const float* w = (gi < 65536) ? w1 : w2;
        unsigned short* wp = (gi < 65536) ? w1p : w2p;
        int p = gi & 65535;
        int n = p >> 8, cin = p & 255;
        const float* src = w + (size_t)p * 3;
        float a[3] = {src[0], src[1], src[2]};
        int nb = n >> 4, nl = n & 15;
        int e = cin & 7, lhi = (cin >> 3) & 3, chi = cin >> 5;
        int base = nb * 512 + (lhi * 16 + nl) * 8 + e;
        #pragma unroll
        for (int kk = 0; kk < 3; ++kk)
            wp[(kk * 8 + chi) * 8192 + base] = f2bf(a[kk]);
    } else {
        __shared__ int s[512];
        int b = blk - 256, tid = threadIdx.x;
        int d = tgt[b * 512 + tid];
        s[tid] = d;
        __syncthreads();
        for (int off = 1; off < 512; off <<= 1) {
            int v = (tid >= off) ? s[tid - off] : 0;
            __syncthreads();
            s[tid] += v;
            __syncthreads();
        }
        int myend = s[tid];          // inclusive cumsum
        int mystart = myend - d;
        short* row = idxT + (size_t)b * M;
        for (int p = mystart; p < myend; ++p) row[p] = (short)tid;
        __syncthreads();
        int total = s[511];
        for (int p = total + tid; p < M; p += 512) row[p] = (short)-1;
    }
}

// ---------------------------------------------------------------------------
// gather part: 32 mel rows / block, 8 waves; idx lookup, plain stores.
// Jobs are parity-interleaved across the two hetero kernels so each carries
// ~half the real (read+write) rows and ~half the tail (write-only) rows.
// base = 0 (even jobs, K1) or 32 (odd jobs, K2); job stride = 64 rows.
// ---------------------------------------------------------------------------
static __device__ __forceinline__ void gather_part(
    int gblk, int base, const float* __restrict__ x,
    const short* __restrict__ idxT, float* __restrict__ out, int M,
    int wv, int lane)
{
    int b = gblk / 56;
    int r0 = (gblk - b * 56) * 64 + base;
    const short* row = idxT + (size_t)b * M;
    int id[4];
    #pragma unroll
    for (int i = 0; i < 4; ++i) id[i] = row[r0 + i * 8 + wv];
    #pragma unroll
    for (int i = 0; i < 4; ++i) {
        int m = r0 + i * 8 + wv;
        float4 v = make_float4(0.f, 0.f, 0.f, 0.f);
        if (id[i] >= 0)
            v = *reinterpret_cast<const float4*>(x + ((size_t)(b * 512 + id[i])) * 256 + lane * 4);
        *reinterpret_cast<float4*>(out + ((size_t)b * M + m) * 256 + lane * 4) = v;
    }
}

// ---------------------------------------------------------------------------
// conv1 + gather (even jobs). BM=64, BN=256; K as 2 cin-halves x 12 BK=32
// tiles; double-buffered B.
// ---------------------------------------------------------------------------
__global__ __launch_bounds__(512, 4) void conv1_hetero(
    const float* __restrict__ x, const unsigned short* __restrict__ Wp,
    const float* __restrict__ bias, const float* __restrict__ g,
    const float* __restrict__ be, unsigned short* __restrict__ h1b,
    const short* __restrict__ idxT, float* __restrict__ out, int M)
{
    __shared__ __align__(16) unsigned short As[66 * 128];
    __shared__ __align__(16) unsigned short Bsm[2][8192];
    __shared__ float lnS[4][64], lnQ[4][64];

    const int tid = threadIdx.x;
    const int lane = tid & 63;
    const int wv = tid >> 6;

    if (blockIdx.x >= 256) {
        gather_part(blockIdx.x - 256, 0, x, idxT, out, M, wv, lane);
        return;
    }

    const int wmi = wv >> 2, wni = wv & 3;
    const int grp = lane >> 4, lr = lane & 15;
    const int b = blockIdx.x >> 3;
    const int t_base = (blockIdx.x & 7) * 64;

    const char* wpB = (const char*)Wp;
    char* bs0 = (char*)&Bsm[0][0];
    #define STAGE_B(ktg, buf) do {                                             \
        const char* _s = wpB + (ktg) * 16384 + wv * 2048 + lane * 16;          \
        char* _d = bs0 + (buf) * 16384 + wv * 2048;                            \
        gll16(_s, _d); gll16(_s + 1024, _d + 1024);                            \
    } while (0)

    f32x4 acc[2][4] = {};
    int cur = 0;

    for (int h = 0; h < 2; ++h) {
        // ---- A-stage: rows t_base-1..t_base+64, cin [h*128, h*128+128)
        #pragma unroll
        for (int i = 0; i < 5; ++i) {
            int cc = i * 512 + tid;                 // 2112 ushort4 chunks
            if (cc < 66 * 32) {
                int row = cc >> 5, ql = cc & 31;
                int tt = t_base - 1 + row;
                ushort4 o = make_ushort4(0, 0, 0, 0);
                if ((unsigned)tt < 512u) {
                    float4 v = *reinterpret_cast<const float4*>(
                        x + ((size_t)(b * 512 + tt)) * 256 + h * 128 + ql * 4);
                    o.x = f2bf(v.x); o.y = f2bf(v.y); o.z = f2bf(v.z); o.w = f2bf(v.w);
                }
                *reinterpret_cast<ushort4*>(&As[row * 128 + ((ql * 4) ^ ((row & 7) << 3))]) = o;
            }
        }
        STAGE_B(h * 4, cur);                        // first tile of this half
        __syncthreads();

        for (int j = 0; j < 12; ++j) {
            if (j < 11) {
                int jn = j + 1;
                STAGE_B((jn >> 2) * 8 + h * 4 + (jn & 3), cur ^ 1);
            }
            const int cbl = j & 3, kk = j >> 2;
            bf16x8 af[2], bfr[4];
            #pragma unroll
            for (int mi = 0; mi < 2; ++mi) {
                int tr = wmi * 32 + mi * 16 + lr + kk;
                af[mi] = *reinterpret_cast<const bf16x8*>(
                    &As[tr * 128 + ((cbl * 32 + grp * 8) ^ ((tr & 7) << 3))]);
            }
            #pragma unroll
            for (int ni = 0; ni < 4; ++ni)
                bfr[ni] = *reinterpret_cast<const bf16x8*>(&Bsm[cur][(wni * 4 + ni) * 512 + lane * 8]);
            __builtin_amdgcn_s_setprio(1);
            #pragma unroll
            for (int mi = 0; mi < 2; ++mi)
                #pragma unroll
                for (int ni = 0; ni < 4; ++ni)
                    acc[mi][ni] = __builtin_amdgcn_mfma_f32_16x16x32_bf16(af[mi], bfr[ni], acc[mi][ni], 0, 0, 0);
            __builtin_amdgcn_s_setprio(0);
            __syncthreads();
            cur ^= 1;
        }
    }

    // ---- epilogue: bias+relu, LN, LDS-staged (Bsm arena, 32KB) bf16 store
    float bcol[4], gcol[4], becol[4];
    #pragma unroll
    for (int ni = 0; ni < 4; ++ni) {
        int col = wni * 64 + ni * 16 + lr;
        bcol[ni] = bias[col]; gcol[ni] = g[col]; becol[ni] = be[col];
    }
    #pragma unroll
    for (int mi = 0; mi < 2; ++mi)
        #pragma unroll
        for (int ni = 0; ni < 4; ++ni)
            #pragma unroll
            for (int r = 0; r < 4; ++r)
                acc[mi][ni][r] = fmaxf(acc[mi][ni][r] + bcol[ni], 0.f);

    #pragma unroll
    for (int mi = 0; mi < 2; ++mi)
        #pragma unroll
        for (int r = 0; r < 4; ++r) {
            float s = acc[mi][0][r] + acc[mi][1][r] + acc[mi][2][r] + acc[mi][3][r];
            float q = acc[mi][0][r] * acc[mi][0][r] + acc[mi][1][r] * acc[mi][1][r]
                    + acc[mi][2][r] * acc[mi][2][r] + acc[mi][3][r] * acc[mi][3][r];
            #pragma unroll
            for (int off = 1; off < 16; off <<= 1) {
                s += __shfl_xor(s, off);
                q += __shfl_xor(q, off);
            }
            if (lr == 0) {
                int R = wmi * 32 + mi * 16 + grp * 4 + r;
                lnS[wni][R] = s; lnQ[wni][R] = q;
            }
        }
    __syncthreads();

    unsigned short* Hs = &Bsm[0][0];   // 32 KB exactly
    #pragma unroll
    for (int mi = 0; mi < 2; ++mi)
        #pragma unroll
        for (int r = 0; r < 4; ++r) {
            int R = wmi * 32 + mi * 16 + grp * 4 + r;
            float mu = (lnS[0][R] + lnS[1][R] + lnS[2][R] + lnS[3][R]) * (1.f / 256.f);
            float var = (lnQ[0][R] + lnQ[1][R] + lnQ[2][R] + lnQ[3][R]) * (1.f / 256.f) - mu * mu;
            float rs = rsqrtf(var + 1e-5f);
            #pragma unroll
            for (int ni = 0; ni < 4; ++ni) {
                int col = wni * 64 + ni * 16 + lr;
                float hv = (acc[mi][ni][r] - mu) * rs * gcol[ni] + becol[ni];
                Hs[R * 256 + (col ^ ((R & 7) << 3))] = f2bf(hv);   // conv2's swizzle
            }
        }
    __syncthreads();
    #pragma unroll
    for (int i = 0; i < 4; ++i) {
        int c = i * 512 + tid;          // 2048 chunks of 16B, coalesced
        int row = c >> 5, seg = c & 31;
        uint4 v = *reinterpret_cast<const uint4*>(&Hs[row * 256 + seg * 8]);
        *reinterpret_cast<uint4*>(h1b + ((size_t)(b * 512 + t_base + row)) * 256 + seg * 8) = v;
    }
    #undef STAGE_B
}

// ---------------------------------------------------------------------------
// conv2 + LN + linear + relu -> dur, + gather (odd jobs)
// ---------------------------------------------------------------------------
__global__ __launch_bounds__(512, 4) void conv2_hetero(
    const unsigned short* __restrict__ h1b, const unsigned short* __restrict__ Wp,
    const float* __restrict__ bias, const float* __restrict__ g,
    const float* __restrict__ be, const float* __restrict__ lw,
    const float* __restrict__ lb, float* __restrict__ dur,
    const short* __restrict__ idxT, const float* __restrict__ x,
    float* __restrict__ out, int M)
{
    __shared__ __align__(16) unsigned short As[66 * 128];
    __shared__ __align__(16) unsigned short Bsm[2][8192];
    __shared__ float lnS[4][64], lnQ[4][64], lnD[4][64];

    const int tid = threadIdx.x;
    const int lane = tid & 63;
    const int wv = tid >> 6;

    if (blockIdx.x >= 256) {
        gather_part(blockIdx.x - 256, 32, x, idxT, out, M, wv, lane);
        return;
    }

    const int wmi = wv >> 2, wni = wv & 3;
    const int grp = lane >> 4, lr = lane & 15;
    const int b = blockIdx.x >> 3;
    const int t_base = (blockIdx.x & 7) * 64;

    const char* wpB = (const char*)Wp;
    const char* h1B = (const char*)h1b;
    char* bs0 = (char*)&Bsm[0][0];
    #define STAGE_B(ktg, buf) do {                                             \
        const char* _s = wpB + (ktg) * 16384 + wv * 2048 + lane * 16;          \
        char* _d = bs0 + (buf) * 16384 + wv * 2048;                            \
        gll16(_s, _d); gll16(_s + 1024, _d + 1024);                            \
    } while (0)

    f32x4 acc[2][4] = {};
    int cur = 0;

    for (int h = 0; h < 2; ++h) {
        // ---- A-stage: interior rows 1..64, half h via per-lane-src gll16
        #pragma unroll
        for (int j2 = 0; j2 < 2; ++j2) {
            int row0 = 1 + wv * 8 + j2 * 4;
            const char* src = h1B
                + ((size_t)(b * 512 + t_base + wv * 8 + j2 * 4 + (lane >> 4))) * 512
                + h * 256 + (lane & 15) * 16;
            gll16(src, (char*)As + row0 * 256);
        }
        // halo rows 0 (t=t_base-1) and 65 (t=t_base+64), 256B each
        if (tid < 16) {
            int tt = t_base - 1;
            uint4 v = make_uint4(0u, 0u, 0u, 0u);
            if (tt >= 0)
                v = *reinterpret_cast<const uint4*>(h1B + ((size_t)(b * 512 + tt)) * 512 + h * 256 + tid * 16);
            *reinterpret_cast<uint4*>((char*)As + tid * 16) = v;
        } else if (tid < 32) {
            int t2 = tid - 16, tt = t_base + 64;
            uint4 v = make_uint4(0u, 0u, 0u, 0u);
            if (tt < 512)
                v = *reinterpret_cast<const uint4*>(h1B + ((size_t)(b * 512 + tt)) * 512 + h * 256 + t2 * 16);
            *reinterpret_cast<uint4*>((char*)As + 65 * 256 + t2 * 16) = v;
        }
        STAGE_B(h * 4, cur);
        __syncthreads();

        for (int j = 0; j < 12; ++j) {
            if (j < 11) {
                int jn = j + 1;
                STAGE_B((jn >> 2) * 8 + h * 4 + (jn & 3), cur ^ 1);
            }
            const int cbl = j & 3, kk = j >> 2;
            bf16x8 af[2], bfr[4];
            #pragma unroll
            for (int mi = 0; mi < 2; ++mi) {
                int tr = wmi * 32 + mi * 16 + lr + kk;
                // swizzle keyed to absolute t: (t_base+tr-1)&7 = (tr+7)&7
                af[mi] = *reinterpret_cast<const bf16x8*>(
                    &As[tr * 128 + ((cbl * 32 + grp * 8) ^ (((tr + 7) & 7) << 3))]);
            }
            #pragma unroll
            for (int ni = 0; ni < 4; ++ni)
                bfr[ni] = *reinterpret_cast<const bf16x8*>(&Bsm[cur][(wni * 4 + ni) * 512 + lane * 8]);
            __builtin_amdgcn_s_setprio(1);
            #pragma unroll
            for (int mi = 0; mi < 2; ++mi)
                #pragma unroll
                for (int ni = 0; ni < 4; ++ni)
                    acc[mi][ni] = __builtin_amdgcn_mfma_f32_16x16x32_bf16(af[mi], bfr[ni], acc[mi][ni], 0, 0, 0);
            __builtin_amdgcn_s_setprio(0);
            __syncthreads();
            cur ^= 1;
        }
    }

    // ---- epilogue: bias+relu, LN, dot lin_w, relu -> dur[64]
    float bcol[4], gcol[4], becol[4], wcol[4];
    #pragma unroll
    for (int ni = 0; ni < 4; ++ni) {
        int col = wni * 64 + ni * 16 + lr;
        bcol[ni] = bias[col]; gcol[ni] = g[col]; becol[ni] = be[col]; wcol[ni] = lw[col];
    }
    #pragma unroll
    for (int mi = 0; mi < 2; ++mi)
        #pragma unroll
        for (int ni = 0; ni < 4; ++ni)
            #pragma unroll
            for (int r = 0; r < 4; ++r)
                acc[mi][ni][r] = fmaxf(acc[mi][ni][r] + bcol[ni], 0.f);

    #pragma unroll
    for (int mi = 0; mi < 2; ++mi)
        #pragma unroll
        for (int r = 0; r < 4; ++r) {
            float s = acc[mi][0][r] + acc[mi][1][r] + acc[mi][2][r] + acc[mi][3][r];
            float q = acc[mi][0][r] * acc[mi][0][r] + acc[mi][1][r] * acc[mi][1][r]
                    + acc[mi][2][r] * acc[mi][2][r] + acc[mi][3][r] * acc[mi][3][r];
            #pragma unroll
            for (int off = 1; off < 16; off <<= 1) {
                s += __shfl_xor(s, off);
                q += __shfl_xor(q, off);
            }
            if (lr == 0) {
                int R = wmi * 32 + mi * 16 + grp * 4 + r;
                lnS[wni][R] = s; lnQ[wni][R] = q;
            }
        }
    __syncthreads();
    #pragma unroll
    for (int mi = 0; mi < 2; ++mi)
        #pragma unroll
        for (int r = 0; r < 4; ++r) {
            int R = wmi * 32 + mi * 16 + grp * 4 + r;
            float mu = (lnS[0][R] + lnS[1][R] + lnS[2][R] + lnS[3][R]) * (1.f / 256.f);
            float var = (lnQ[0][R] + lnQ[1][R] + lnQ[2][R] + lnQ[3][R]) * (1.f / 256.f) - mu * mu;
            float rs = rsqrtf(var + 1e-5f);
            float d = ((acc[mi][0][r] - mu) * rs * gcol[0] + becol[0]) * wcol[0]
                    + ((acc[mi][1][r] - mu) * rs * gcol[1] + becol[1]) * wcol[1]
                    + ((acc[mi][2][r] - mu) * rs * gcol[2] + becol[2]) * wcol[2]
                    + ((acc[mi][3][r] - mu) * rs * gcol[3] + becol[3]) * wcol[3];
            #pragma unroll
            for (int off = 1; off < 16; off <<= 1) d += __shfl_xor(d, off);
            if (lr == 0) lnD[wni][R] = d;
        }
    __syncthreads();
    if (tid < 64) {
        float dd = lnD[0][tid] + lnD[1][tid] + lnD[2][tid] + lnD[3][tid] + lb[0];
        dur[(size_t)b * 512 + t_base + tid] = fmaxf(dd, 0.f);
    }
    #undef STAGE_B
}

extern "C" void kernel_launch(void* const* d_in, const int* in_sizes, int n_in,
                              void* d_out, int out_size, void* d_ws, size_t ws_size,
                              hipStream_t stream) {
    const float* x   = (const float*)d_in[0];
    const float* w1  = (const float*)d_in[1];
    const float* b1  = (const float*)d_in[2];
    const float* g1  = (const float*)d_in[3];
    const float* be1 = (const float*)d_in[4];
    const float* w2  = (const float*)d_in[5];
    const float* b2  = (const float*)d_in[6];
    const float* g2  = (const float*)d_in[7];
    const float* be2 = (const float*)d_in[8];
    const float* lw  = (const float*)d_in[9];
    const float* lb  = (const float*)d_in[10];
    const int* tgt   = (const int*)d_in[11];
    float* out = (float*)d_out;

    const int B = 32, T = 512, C = 256;
    const int rows = B * T;                       // 16384
    const int M = (out_size - rows) / (B * C);    // 3584

    char* ws = (char*)d_ws;
    unsigned short* w1p = (unsigned short*)(ws);              //   393,216 B
    unsigned short* w2p = (unsigned short*)(ws + 393216);     //   393,216 B
    unsigned short* h1b = (unsigned short*)(ws + 786432);     // 8,388,608 B
    short* idxT         = (short*)(ws + 9175040);             //   229,376 B

    prep<<<288, 512, 0, stream>>>(w1, w2, w1p, w2p, tgt, idxT, M);
    // K1: 256 conv blocks + 32*56 gather blocks (EVEN 32-row jobs)
    conv1_hetero<<<2048, 512, 0, stream>>>(x, w1p, b1, g1, be1, h1b, idxT, out, M);
    // K2: 256 conv blocks + 32*56 gather blocks (ODD 32-row jobs)
    conv2_hetero<<<2048, 512, 0, stream>>>(h1b, w2p, b2, g2, be2, lw, lb,
                                           out + (size_t)B * M * C, idxT, x, out, M);
}

// Round 15
// 53.550 us; speedup vs baseline: 5.8051x; 1.0784x over previous
//
#include <hip/hip_runtime.h>
#include <hip/hip_bf16.h>

typedef float f32x4 __attribute__((ext_vector_type(4)));
typedef __bf16 bf16x8 __attribute__((ext_vector_type(8)));

static __device__ __forceinline__ unsigned short f2bf(float f) {
    unsigned int u = __float_as_uint(f);
    unsigned int r = (u + 0x7fffu + ((u >> 16) & 1u)) >> 16;   // RNE
    return (unsigned short)r;
}

static __device__ __forceinline__ void gll16(const void* g, void* l) {
    __builtin_amdgcn_global_load_lds(
        (const __attribute__((address_space(1))) unsigned int*)g,
        (__attribute__((address_space(3))) unsigned int*)l, 16, 0, 0);
}

// ---------------------------------------------------------------------------
// prep: pack conv weights (tile-major MFMA-ready, coalesced reads) +
// cumsum + idx-expand.  (unchanged, proven)
// ---------------------------------------------------------------------------
__global__ __launch_bounds__(512) void prep(
    const float* __restrict__ w1, const float* __restrict__ w2,
    unsigned short* __restrict__ w1p, unsigned short* __restrict__ w2p,
    const int* __restrict__ tgt, short* __restrict__ idxT, int M)
{
    int blk = blockIdx.x;
    if (blk < 256) {
        int gi = blk * 512 + threadIdx.x;            // pair index (n,cin)
        const float* w = (gi < 65536) ? w1 : w2;
        unsigned short* wp = (gi < 65536) ? w1p : w2p;
        int p = gi & 65535;
        int n = p >> 8, cin = p & 255;
        const float* src = w + (size_t)p * 3;
        float a[3] = {src[0], src[1], src[2]};
        int nb = n >> 4, nl = n & 15;
        int e = cin & 7, lhi = (cin >> 3) & 3, chi = cin >> 5;
        int base = nb * 512 + (lhi * 16 + nl) * 8 + e;
        #pragma unroll
        for (int kk = 0; kk < 3; ++kk)
            wp[(kk * 8 + chi) * 8192 + base] = f2bf(a[kk]);
    } else {
        __shared__ int s[512];
        int b = blk - 256, tid = threadIdx.x;
        int d = tgt[b * 512 + tid];
        s[tid] = d;
        __syncthreads();
        for (int off = 1; off < 512; off <<= 1) {
            int v = (tid >= off) ? s[tid - off] : 0;
            __syncthreads();
            s[tid] += v;
            __syncthreads();
        }
        int myend = s[tid];
        int mystart = myend - d;
        short* row = idxT + (size_t)b * M;
        for (int p = mystart; p < myend; ++p) row[p] = (short)tid;
        __syncthreads();
        int total = s[511];
        for (int p = total + tid; p < M; p += 512) row[p] = (short)-1;
    }
}

// ---------------------------------------------------------------------------
// Fused conv1+conv2 (halo recompute, H resident in LDS) + full gather.
// Conv blocks: 288 (= 32 batches x 9 tiles of output-stride 62).
// Gather blocks: 1792 (64 mel rows each, 8 rows per wave).
// ---------------------------------------------------------------------------
__global__ __launch_bounds__(512, 4) void fused(
    const float* __restrict__ x,
    const unsigned short* __restrict__ w1p, const float* __restrict__ b1,
    const float* __restrict__ g1, const float* __restrict__ be1,
    const unsigned short* __restrict__ w2p, const float* __restrict__ b2,
    const float* __restrict__ g2, const float* __restrict__ be2,
    const float* __restrict__ lw, const float* __restrict__ lb,
    float* __restrict__ dur, const short* __restrict__ idxT,
    float* __restrict__ out, int M)
{
    __shared__ __align__(16) unsigned short H[64 * 256];    // 32 KB h1 tile
    __shared__ __align__(16) unsigned short As[66 * 64];    // 8.25 KB x quarter
    __shared__ __align__(16) unsigned short Bsm[2][8192];   // 32 KB W dbuf
    __shared__ float lnS[4][64], lnQ[4][64], lnD[4][64];

    const int tid = threadIdx.x;
    const int lane = tid & 63;
    const int wv = tid >> 6;

    if (blockIdx.x >= 288) {
        // ---- gather: 64 rows, idx lookup, plain stores
        int gid = blockIdx.x - 288;
        int b = gid / 56;
        int r0 = (gid - b * 56) * 64;
        const short* row = idxT + (size_t)b * M;
        int id[8];
        #pragma unroll
        for (int i = 0; i < 8; ++i) id[i] = row[r0 + i * 8 + wv];
        #pragma unroll
        for (int i = 0; i < 8; ++i) {
            int m = r0 + i * 8 + wv;
            float4 v = make_float4(0.f, 0.f, 0.f, 0.f);
            if (id[i] >= 0)
                v = *reinterpret_cast<const float4*>(x + ((size_t)(b * 512 + id[i])) * 256 + lane * 4);
            *reinterpret_cast<float4*>(out + ((size_t)b * M + m) * 256 + lane * 4) = v;
        }
        return;
    }

    const int wmi = wv >> 2, wni = wv & 3;
    const int grp = lane >> 4, lr = lane & 15;
    const int b = blockIdx.x / 9;
    const int t0 = (blockIdx.x - b * 9) * 62;     // output window [t0, t0+62)

    char* bs0 = (char*)&Bsm[0][0];
    #define STAGE_B(basep, ktg, buf) do {                                      \
        const char* _s = (const char*)(basep) + (ktg) * 16384 + wv * 2048 + lane * 16; \
        char* _d = bs0 + (buf) * 16384 + wv * 2048;                            \
        gll16(_s, _d); gll16(_s + 1024, _d + 1024);                            \
    } while (0)

    // ===================== CONV1: h1[t0-1 .. t0+62] -> H =====================
    f32x4 acc[2][4] = {};
    int cur = 0;
    for (int h = 0; h < 4; ++h) {                 // cin quarter [h*64, h*64+64)
        // A-stage: As rows i=0..65 <-> x row t0-2+i, quarter h, swizzled
        #pragma unroll
        for (int i = 0; i < 3; ++i) {
            int cc = i * 512 + tid;               // 1056 ushort4 chunks
            if (cc < 66 * 16) {
                int row = cc >> 4, ql = cc & 15;
                int tt = t0 - 2 + row;
                ushort4 o = make_ushort4(0, 0, 0, 0);
                if ((unsigned)tt < 512u) {
                    float4 v = *reinterpret_cast<const float4*>(
                        x + ((size_t)(b * 512 + tt)) * 256 + h * 64 + ql * 4);
                    o.x = f2bf(v.x); o.y = f2bf(v.y); o.z = f2bf(v.z); o.w = f2bf(v.w);
                }
                *reinterpret_cast<ushort4*>(&As[row * 64 + ((ql * 4) ^ ((row & 7) << 3))]) = o;
            }
        }
        if (h == 0) STAGE_B(w1p, 0, cur);         // ktg = kk*8 + h*2 + cbl = 0
        __syncthreads();

        for (int j = 0; j < 6; ++j) {             // kk = j>>1, cbl = j&1
            if (j < 5) {
                int jn = j + 1;
                STAGE_B(w1p, (jn >> 1) * 8 + h * 2 + (jn & 1), cur ^ 1);
            } else if (h < 3) {
                STAGE_B(w1p, (h + 1) * 2, cur ^ 1);          // next quarter tile 0
            } else {
                STAGE_B(w2p, 0, cur ^ 1);                    // conv2 tile 0
            }
            const int kk = j >> 1, cbl = j & 1;
            bf16x8 af[2], bfr[4];
            #pragma unroll
            for (int mi = 0; mi < 2; ++mi) {
                int tr = wmi * 32 + mi * 16 + lr + kk;       // As row (<=65)
                af[mi] = *reinterpret_cast<const bf16x8*>(
                    &As[tr * 64 + ((cbl * 32 + grp * 8) ^ ((tr & 7) << 3))]);
            }
            #pragma unroll
            for (int ni = 0; ni < 4; ++ni)
                bfr[ni] = *reinterpret_cast<const bf16x8*>(&Bsm[cur][(wni * 4 + ni) * 512 + lane * 8]);
            __builtin_amdgcn_s_setprio(1);
            #pragma unroll
            for (int mi = 0; mi < 2; ++mi)
                #pragma unroll
                for (int ni = 0; ni < 4; ++ni)
                    acc[mi][ni] = __builtin_amdgcn_mfma_f32_16x16x32_bf16(af[mi], bfr[ni], acc[mi][ni], 0, 0, 0);
            __builtin_amdgcn_s_setprio(0);
            __syncthreads();
            cur ^= 1;
        }
    }

    // ---- conv1 epilogue: bias+relu, LN, store H (bf16, swizzled, zero-guard)
    {
        float bcol[4], gcol[4], becol[4];
        #pragma unroll
        for (int ni = 0; ni < 4; ++ni) {
            int col = wni * 64 + ni * 16 + lr;
            bcol[ni] = b1[col]; gcol[ni] = g1[col]; becol[ni] = be1[col];
        }
        #pragma unroll
        for (int mi = 0; mi < 2; ++mi)
            #pragma unroll
            for (int ni = 0; ni < 4; ++ni)
                #pragma unroll
                for (int r = 0; r < 4; ++r)
                    acc[mi][ni][r] = fmaxf(acc[mi][ni][r] + bcol[ni], 0.f);

        #pragma unroll
        for (int mi = 0; mi < 2; ++mi)
            #pragma unroll
            for (int r = 0; r < 4; ++r) {
                float s = acc[mi][0][r] + acc[mi][1][r] + acc[mi][2][r] + acc[mi][3][r];
                float q = acc[mi][0][r] * acc[mi][0][r] + acc[mi][1][r] * acc[mi][1][r]
                        + acc[mi][2][r] * acc[mi][2][r] + acc[mi][3][r] * acc[mi][3][r];
                #pragma unroll
                for (int off = 1; off < 16; off <<= 1) {
                    s += __shfl_xor(s, off);
                    q += __shfl_xor(q, off);
                }
                if (lr == 0) {
                    int R = wmi * 32 + mi * 16 + grp * 4 + r;
                    lnS[wni][R] = s; lnQ[wni][R] = q;
                }
            }
        __syncthreads();
        #pragma unroll
        for (int mi = 0; mi < 2; ++mi)
            #pragma unroll
            for (int r = 0; r < 4; ++r) {
                int R = wmi * 32 + mi * 16 + grp * 4 + r;    // h1 row t = t0-1+R
                int t = t0 - 1 + R;
                float valid = ((unsigned)t < 512u) ? 1.f : 0.f;
                float mu = (lnS[0][R] + lnS[1][R] + lnS[2][R] + lnS[3][R]) * (1.f / 256.f);
                float var = (lnQ[0][R] + lnQ[1][R] + lnQ[2][R] + lnQ[3][R]) * (1.f / 256.f) - mu * mu;
                float rs = rsqrtf(var + 1e-5f);
                #pragma unroll
                for (int ni = 0; ni < 4; ++ni) {
                    int col = wni * 64 + ni * 16 + lr;
                    float hv = ((acc[mi][ni][r] - mu) * rs * gcol[ni] + becol[ni]) * valid;
                    H[R * 256 + (col ^ ((R & 7) << 3))] = f2bf(hv);
                }
            }
        __syncthreads();   // H complete; w2p tile 0 staged (drained by barrier)
    }

    // ===================== CONV2: reads H, -> dur =====================
    f32x4 acc2[2][4] = {};
    for (int h = 0; h < 4; ++h) {
        for (int j = 0; j < 6; ++j) {
            if (j < 5) {
                int jn = j + 1;
                STAGE_B(w2p, (jn >> 1) * 8 + h * 2 + (jn & 1), cur ^ 1);
            } else if (h < 3) {
                STAGE_B(w2p, (h + 1) * 2, cur ^ 1);
            }
            const int kk = j >> 1, cbl = j & 1;
            bf16x8 af[2], bfr[4];
            #pragma unroll
            for (int mi = 0; mi < 2; ++mi) {
                int tr = wmi * 32 + mi * 16 + lr + kk - 1;   // H row, clamp
                int trc = tr < 0 ? 0 : (tr > 63 ? 63 : tr);  // only hits discarded rows
                af[mi] = *reinterpret_cast<const bf16x8*>(
                    &H[trc * 256 + ((h * 64 + cbl * 32 + grp * 8) ^ ((trc & 7) << 3))]);
            }
            #pragma unroll
            for (int ni = 0; ni < 4; ++ni)
                bfr[ni] = *reinterpret_cast<const bf16x8*>(&Bsm[cur][(wni * 4 + ni) * 512 + lane * 8]);
            __builtin_amdgcn_s_setprio(1);
            #pragma unroll
            for (int mi = 0; mi < 2; ++mi)
                #pragma unroll
                for (int ni = 0; ni < 4; ++ni)
                    acc2[mi][ni] = __builtin_amdgcn_mfma_f32_16x16x32_bf16(af[mi], bfr[ni], acc2[mi][ni], 0, 0, 0);
            __builtin_amdgcn_s_setprio(0);
            __syncthreads();
            cur ^= 1;
        }
    }

    // ---- conv2 epilogue: bias+relu, LN, dot lin_w, relu -> dur rows 1..62
    {
        float bcol[4], gcol[4], becol[4], wcol[4];
        #pragma unroll
        for (int ni = 0; ni < 4; ++ni) {
            int col = wni * 64 + ni * 16 + lr;
            bcol[ni] = b2[col]; gcol[ni] = g2[col]; becol[ni] = be2[col]; wcol[ni] = lw[col];
        }
        #pragma unroll
        for (int mi = 0; mi < 2; ++mi)
            #pragma unroll
            for (int ni = 0; ni < 4; ++ni)
                #pragma unroll
                for (int r = 0; r < 4; ++r)
                    acc2[mi][ni][r] = fmaxf(acc2[mi][ni][r] + bcol[ni], 0.f);

        #pragma unroll
        for (int mi = 0; mi < 2; ++mi)
            #pragma unroll
            for (int r = 0; r < 4; ++r) {
                float s = acc2[mi][0][r] + acc2[mi][1][r] + acc2[mi][2][r] + acc2[mi][3][r];
                float q = acc2[mi][0][r] * acc2[mi][0][r] + acc2[mi][1][r] * acc2[mi][1][r]
                        + acc2[mi][2][r] * acc2[mi][2][r] + acc2[mi][3][r] * acc2[mi][3][r];
                #pragma unroll
                for (int off = 1; off < 16; off <<= 1) {
                    s += __shfl_xor(s, off);
                    q += __shfl_xor(q, off);
                }
                if (lr == 0) {
                    int R = wmi * 32 + mi * 16 + grp * 4 + r;
                    lnS[wni][R] = s; lnQ[wni][R] = q;
                }
            }
        __syncthreads();
        #pragma unroll
        for (int mi = 0; mi < 2; ++mi)
            #pragma unroll
            for (int r = 0; r < 4; ++r) {
                int R = wmi * 32 + mi * 16 + grp * 4 + r;
                float mu = (lnS[0][R] + lnS[1][R] + lnS[2][R] + lnS[3][R]) * (1.f / 256.f);
                float var = (lnQ[0][R] + lnQ[1][R] + lnQ[2][R] + lnQ[3][R]) * (1.f / 256.f) - mu * mu;
                float rs = rsqrtf(var + 1e-5f);
                float d = ((acc2[mi][0][r] - mu) * rs * gcol[0] + becol[0]) * wcol[0]
                        + ((acc2[mi][1][r] - mu) * rs * gcol[1] + becol[1]) * wcol[1]
                        + ((acc2[mi][2][r] - mu) * rs * gcol[2] + becol[2]) * wcol[2]
                        + ((acc2[mi][3][r] - mu) * rs * gcol[3] + becol[3]) * wcol[3];
                #pragma unroll
                for (int off = 1; off < 16; off <<= 1) d += __shfl_xor(d, off);
                if (lr == 0) lnD[wni][R] = d;
            }
        __syncthreads();
        if (tid < 64) {
            int R = tid;
            int t = t0 - 1 + R;
            if (R >= 1 && R <= 62 && t < 512) {
                float dd = lnD[0][R] + lnD[1][R] + lnD[2][R] + lnD[3][R] + lb[0];
                dur[(size_t)b * 512 + t] = fmaxf(dd, 0.f);
            }
        }
    }
    #undef STAGE_B
}

extern "C" void kernel_launch(void* const* d_in, const int* in_sizes, int n_in,
                              void* d_out, int out_size, void* d_ws, size_t ws_size,
                              hipStream_t stream) {
    const float* x   = (const float*)d_in[0];
    const float* w1  = (const float*)d_in[1];
    const float* b1  = (const float*)d_in[2];
    const float* g1  = (const float*)d_in[3];
    const float* be1 = (const float*)d_in[4];
    const float* w2  = (const float*)d_in[5];
    const float* b2  = (const float*)d_in[6];
    const float* g2  = (const float*)d_in[7];
    const float* be2 = (const float*)d_in[8];
    const float* lw  = (const float*)d_in[9];
    const float* lb  = (const float*)d_in[10];
    const int* tgt   = (const int*)d_in[11];
    float* out = (float*)d_out;

    const int B = 32, T = 512, C = 256;
    const int rows = B * T;                       // 16384
    const int M = (out_size - rows) / (B * C);    // 3584

    char* ws = (char*)d_ws;
    unsigned short* w1p = (unsigned short*)(ws);              //   393,216 B
    unsigned short* w2p = (unsigned short*)(ws + 393216);     //   393,216 B
    short* idxT         = (short*)(ws + 786432);              //   229,376 B

    prep<<<288, 512, 0, stream>>>(w1, w2, w1p, w2p, tgt, idxT, M);
    // 288 fused-conv blocks + 1792 gather blocks
    fused<<<2080, 512, 0, stream>>>(x, w1p, b1, g1, be1, w2p, b2, g2, be2,
                                    lw, lb, out + (size_t)B * M * C, idxT, out, M);
}

// Round 16
// 50.143 us; speedup vs baseline: 6.1995x; 1.0679x over previous
//
#include <hip/hip_runtime.h>
#include <hip/hip_bf16.h>

typedef float f32x4 __attribute__((ext_vector_type(4)));
typedef __bf16 bf16x8 __attribute__((ext_vector_type(8)));

static __device__ __forceinline__ unsigned short f2bf(float f) {
    unsigned int u = __float_as_uint(f);
    unsigned int r = (u + 0x7fffu + ((u >> 16) & 1u)) >> 16;   // RNE
    return (unsigned short)r;
}

// ---------------------------------------------------------------------------
// prep: pack conv weights (tile-major MFMA-ready, coalesced reads) +
// cumsum + idx-expand.  (unchanged, proven)
// ---------------------------------------------------------------------------
__global__ __launch_bounds__(512) void prep(
    const float* __restrict__ w1, const float* __restrict__ w2,
    unsigned short* __restrict__ w1p, unsigned short* __restrict__ w2p,
    const int* __restrict__ tgt, short* __restrict__ idxT, int M)
{
    int blk = blockIdx.x;
    if (blk < 256) {
        int gi = blk * 512 + threadIdx.x;            // pair index (n,cin)
        const float* w = (gi < 65536) ? w1 : w2;
        unsigned short* wp = (gi < 65536) ? w1p : w2p;
        int p = gi & 65535;
        int n = p >> 8, cin = p & 255;
        const float* src = w + (size_t)p * 3;
        float a[3] = {src[0], src[1], src[2]};
        int nb = n >> 4, nl = n & 15;
        int e = cin & 7, lhi = (cin >> 3) & 3, chi = cin >> 5;
        int base = nb * 512 + (lhi * 16 + nl) * 8 + e;
        #pragma unroll
        for (int kk = 0; kk < 3; ++kk)
            wp[(kk * 8 + chi) * 8192 + base] = f2bf(a[kk]);
    } else {
        __shared__ int s[512];
        int b = blk - 256, tid = threadIdx.x;
        int d = tgt[b * 512 + tid];
        s[tid] = d;
        __syncthreads();
        for (int off = 1; off < 512; off <<= 1) {
            int v = (tid >= off) ? s[tid - off] : 0;
            __syncthreads();
            s[tid] += v;
            __syncthreads();
        }
        int myend = s[tid];
        int mystart = myend - d;
        short* row = idxT + (size_t)b * M;
        for (int p = mystart; p < myend; ++p) row[p] = (short)tid;
        __syncthreads();
        int total = s[511];
        for (int p = total + tid; p < M; p += 512) row[p] = (short)-1;
    }
}

// ---------------------------------------------------------------------------
// Fused conv1+conv2 (halo recompute, H in LDS, W-frags from global/L2) +
// full gather. Conv blocks: 288 (32 batches x 9 tiles, output stride 62).
// Gather blocks: 1792 (64 mel rows each). LDS = 44.3 KB, no B staging.
// ---------------------------------------------------------------------------
__global__ __launch_bounds__(512, 4) void fused(
    const float* __restrict__ x,
    const unsigned short* __restrict__ w1p, const float* __restrict__ b1,
    const float* __restrict__ g1, const float* __restrict__ be1,
    const unsigned short* __restrict__ w2p, const float* __restrict__ b2,
    const float* __restrict__ g2, const float* __restrict__ be2,
    const float* __restrict__ lw, const float* __restrict__ lb,
    float* __restrict__ dur, const short* __restrict__ idxT,
    float* __restrict__ out, int M)
{
    __shared__ __align__(16) unsigned short H[64 * 256];    // 32 KB h1 tile
    __shared__ __align__(16) unsigned short As[66 * 64];    // 8.25 KB x quarter
    __shared__ float lnS[4][64], lnQ[4][64], lnD[4][64];

    const int tid = threadIdx.x;
    const int lane = tid & 63;
    const int wv = tid >> 6;

    if (blockIdx.x >= 288) {
        // ---- gather: 64 rows, idx lookup, plain stores
        int gid = blockIdx.x - 288;
        int b = gid / 56;
        int r0 = (gid - b * 56) * 64;
        const short* row = idxT + (size_t)b * M;
        int id[8];
        #pragma unroll
        for (int i = 0; i < 8; ++i) id[i] = row[r0 + i * 8 + wv];
        #pragma unroll
        for (int i = 0; i < 8; ++i) {
            int m = r0 + i * 8 + wv;
            float4 v = make_float4(0.f, 0.f, 0.f, 0.f);
            if (id[i] >= 0)
                v = *reinterpret_cast<const float4*>(x + ((size_t)(b * 512 + id[i])) * 256 + lane * 4);
            *reinterpret_cast<float4*>(out + ((size_t)b * M + m) * 256 + lane * 4) = v;
        }
        return;
    }

    const int wmi = wv >> 2, wni = wv & 3;
    const int grp = lane >> 4, lr = lane & 15;
    const int b = blockIdx.x / 9;
    const int t0 = (blockIdx.x - b * 9) * 62;     // output window [t0, t0+62)

    // per-lane W-frag base offset (ushorts) within a tile
    const int wfoff = (wni * 4) * 512 + lane * 8;

    #define LOADW(dst, wp, ktg) do {                                           \
        const unsigned short* _p = (wp) + (size_t)(ktg) * 8192 + wfoff;        \
        dst[0] = *reinterpret_cast<const bf16x8*>(_p);                         \
        dst[1] = *reinterpret_cast<const bf16x8*>(_p + 512);                   \
        dst[2] = *reinterpret_cast<const bf16x8*>(_p + 1024);                  \
        dst[3] = *reinterpret_cast<const bf16x8*>(_p + 1536);                  \
    } while (0)

    // ===================== CONV1: h1[t0-1 .. t0+62] -> H =====================
    f32x4 acc[2][4] = {};
    for (int h = 0; h < 4; ++h) {                 // cin quarter [h*64, h*64+64)
        // A-stage: As rows i=0..65 <-> x row t0-2+i, quarter h, swizzled
        #pragma unroll
        for (int i = 0; i < 3; ++i) {
            int cc = i * 512 + tid;               // 1056 ushort4 chunks
            if (cc < 66 * 16) {
                int row = cc >> 4, ql = cc & 15;
                int tt = t0 - 2 + row;
                ushort4 o = make_ushort4(0, 0, 0, 0);
                if ((unsigned)tt < 512u) {
                    float4 v = *reinterpret_cast<const float4*>(
                        x + ((size_t)(b * 512 + tt)) * 256 + h * 64 + ql * 4);
                    o.x = f2bf(v.x); o.y = f2bf(v.y); o.z = f2bf(v.z); o.w = f2bf(v.w);
                }
                *reinterpret_cast<ushort4*>(&As[row * 64 + ((ql * 4) ^ ((row & 7) << 3))]) = o;
            }
        }
        __syncthreads();                          // As ready

        #pragma unroll
        for (int j = 0; j < 6; ++j) {             // kk = j>>1, cbl = j&1
            const int kk = j >> 1, cbl = j & 1;
            const int ktg = kk * 8 + h * 2 + cbl;
            bf16x8 bw[4], af[2];
            LOADW(bw, w1p, ktg);
            #pragma unroll
            for (int mi = 0; mi < 2; ++mi) {
                int tr = wmi * 32 + mi * 16 + lr + kk;
                af[mi] = *reinterpret_cast<const bf16x8*>(
                    &As[tr * 64 + ((cbl * 32 + grp * 8) ^ ((tr & 7) << 3))]);
            }
            __builtin_amdgcn_s_setprio(1);
            #pragma unroll
            for (int mi = 0; mi < 2; ++mi)
                #pragma unroll
                for (int ni = 0; ni < 4; ++ni)
                    acc[mi][ni] = __builtin_amdgcn_mfma_f32_16x16x32_bf16(af[mi], bw[ni], acc[mi][ni], 0, 0, 0);
            __builtin_amdgcn_s_setprio(0);
        }
        __syncthreads();                          // As reads done before next h
    }

    // ---- conv1 epilogue: bias+relu, LN, store H (bf16, swizzled, zero-guard)
    {
        float bcol[4], gcol[4], becol[4];
        #pragma unroll
        for (int ni = 0; ni < 4; ++ni) {
            int col = wni * 64 + ni * 16 + lr;
            bcol[ni] = b1[col]; gcol[ni] = g1[col]; becol[ni] = be1[col];
        }
        #pragma unroll
        for (int mi = 0; mi < 2; ++mi)
            #pragma unroll
            for (int ni = 0; ni < 4; ++ni)
                #pragma unroll
                for (int r = 0; r < 4; ++r)
                    acc[mi][ni][r] = fmaxf(acc[mi][ni][r] + bcol[ni], 0.f);

        #pragma unroll
        for (int mi = 0; mi < 2; ++mi)
            #pragma unroll
            for (int r = 0; r < 4; ++r) {
                float s = acc[mi][0][r] + acc[mi][1][r] + acc[mi][2][r] + acc[mi][3][r];
                float q = acc[mi][0][r] * acc[mi][0][r] + acc[mi][1][r] * acc[mi][1][r]
                        + acc[mi][2][r] * acc[mi][2][r] + acc[mi][3][r] * acc[mi][3][r];
                #pragma unroll
                for (int off = 1; off < 16; off <<= 1) {
                    s += __shfl_xor(s, off);
                    q += __shfl_xor(q, off);
                }
                if (lr == 0) {
                    int R = wmi * 32 + mi * 16 + grp * 4 + r;
                    lnS[wni][R] = s; lnQ[wni][R] = q;
                }
            }
        __syncthreads();
        #pragma unroll
        for (int mi = 0; mi < 2; ++mi)
            #pragma unroll
            for (int r = 0; r < 4; ++r) {
                int R = wmi * 32 + mi * 16 + grp * 4 + r;    // h1 row t = t0-1+R
                int t = t0 - 1 + R;
                float valid = ((unsigned)t < 512u) ? 1.f : 0.f;
                float mu = (lnS[0][R] + lnS[1][R] + lnS[2][R] + lnS[3][R]) * (1.f / 256.f);
                float var = (lnQ[0][R] + lnQ[1][R] + lnQ[2][R] + lnQ[3][R]) * (1.f / 256.f) - mu * mu;
                float rs = rsqrtf(var + 1e-5f);
                #pragma unroll
                for (int ni = 0; ni < 4; ++ni) {
                    int col = wni * 64 + ni * 16 + lr;
                    float hv = ((acc[mi][ni][r] - mu) * rs * gcol[ni] + becol[ni]) * valid;
                    H[R * 256 + (col ^ ((R & 7) << 3))] = f2bf(hv);
                }
            }
        __syncthreads();   // H complete
    }

    // ===================== CONV2: reads H + global W, no barriers ==========
    f32x4 acc2[2][4] = {};
    #pragma unroll
    for (int h = 0; h < 4; ++h) {
        #pragma unroll
        for (int j = 0; j < 6; ++j) {
            const int kk = j >> 1, cbl = j & 1;
            const int ktg = kk * 8 + h * 2 + cbl;
            bf16x8 bw[4], af[2];
            LOADW(bw, w2p, ktg);
            #pragma unroll
            for (int mi = 0; mi < 2; ++mi) {
                int tr = wmi * 32 + mi * 16 + lr + kk - 1;   // H row, clamp
                int trc = tr < 0 ? 0 : (tr > 63 ? 63 : tr);  // only discarded rows
                af[mi] = *reinterpret_cast<const bf16x8*>(
                    &H[trc * 256 + ((h * 64 + cbl * 32 + grp * 8) ^ ((trc & 7) << 3))]);
            }
            __builtin_amdgcn_s_setprio(1);
            #pragma unroll
            for (int mi = 0; mi < 2; ++mi)
                #pragma unroll
                for (int ni = 0; ni < 4; ++ni)
                    acc2[mi][ni] = __builtin_amdgcn_mfma_f32_16x16x32_bf16(af[mi], bw[ni], acc2[mi][ni], 0, 0, 0);
            __builtin_amdgcn_s_setprio(0);
        }
    }

    // ---- conv2 epilogue: bias+relu, LN, dot lin_w, relu -> dur rows 1..62
    {
        float bcol[4], gcol[4], becol[4], wcol[4];
        #pragma unroll
        for (int ni = 0; ni < 4; ++ni) {
            int col = wni * 64 + ni * 16 + lr;
            bcol[ni] = b2[col]; gcol[ni] = g2[col]; becol[ni] = be2[col]; wcol[ni] = lw[col];
        }
        #pragma unroll
        for (int mi = 0; mi < 2; ++mi)
            #pragma unroll
            for (int ni = 0; ni < 4; ++ni)
                #pragma unroll
                for (int r = 0; r < 4; ++r)
                    acc2[mi][ni][r] = fmaxf(acc2[mi][ni][r] + bcol[ni], 0.f);

        #pragma unroll
        for (int mi = 0; mi < 2; ++mi)
            #pragma unroll
            for (int r = 0; r < 4; ++r) {
                float s = acc2[mi][0][r] + acc2[mi][1][r] + acc2[mi][2][r] + acc2[mi][3][r];
                float q = acc2[mi][0][r] * acc2[mi][0][r] + acc2[mi][1][r] * acc2[mi][1][r]
                        + acc2[mi][2][r] * acc2[mi][2][r] + acc2[mi][3][r] * acc2[mi][3][r];
                #pragma unroll
                for (int off = 1; off < 16; off <<= 1) {
                    s += __shfl_xor(s, off);
                    q += __shfl_xor(q, off);
                }
                if (lr == 0) {
                    int R = wmi * 32 + mi * 16 + grp * 4 + r;
                    lnS[wni][R] = s; lnQ[wni][R] = q;
                }
            }
        __syncthreads();
        #pragma unroll
        for (int mi = 0; mi < 2; ++mi)
            #pragma unroll
            for (int r = 0; r < 4; ++r) {
                int R = wmi * 32 + mi * 16 + grp * 4 + r;
                float mu = (lnS[0][R] + lnS[1][R] + lnS[2][R] + lnS[3][R]) * (1.f / 256.f);
                float var = (lnQ[0][R] + lnQ[1][R] + lnQ[2][R] + lnQ[3][R]) * (1.f / 256.f) - mu * mu;
                float rs = rsqrtf(var + 1e-5f);
                float d = ((acc2[mi][0][r] - mu) * rs * gcol[0] + becol[0]) * wcol[0]
                        + ((acc2[mi][1][r] - mu) * rs * gcol[1] + becol[1]) * wcol[1]
                        + ((acc2[mi][2][r] - mu) * rs * gcol[2] + becol[2]) * wcol[2]
                        + ((acc2[mi][3][r] - mu) * rs * gcol[3] + becol[3]) * wcol[3];
                #pragma unroll
                for (int off = 1; off < 16; off <<= 1) d += __shfl_xor(d, off);
                if (lr == 0) lnD[wni][R] = d;
            }
        __syncthreads();
        if (tid < 64) {
            int R = tid;
            int t = t0 - 1 + R;
            if (R >= 1 && R <= 62 && t < 512) {
                float dd = lnD[0][R] + lnD[1][R] + lnD[2][R] + lnD[3][R] + lb[0];
                dur[(size_t)b * 512 + t] = fmaxf(dd, 0.f);
            }
        }
    }
    #undef LOADW
}

extern "C" void kernel_launch(void* const* d_in, const int* in_sizes, int n_in,
                              void* d_out, int out_size, void* d_ws, size_t ws_size,
                              hipStream_t stream) {
    const float* x   = (const float*)d_in[0];
    const float* w1  = (const float*)d_in[1];
    const float* b1  = (const float*)d_in[2];
    const float* g1  = (const float*)d_in[3];
    const float* be1 = (const float*)d_in[4];
    const float* w2  = (const float*)d_in[5];
    const float* b2  = (const float*)d_in[6];
    const float* g2  = (const float*)d_in[7];
    const float* be2 = (const float*)d_in[8];
    const float* lw  = (const float*)d_in[9];
    const float* lb  = (const float*)d_in[10];
    const int* tgt   = (const int*)d_in[11];
    float* out = (float*)d_out;

    const int B = 32, T = 512, C = 256;
    const int rows = B * T;                       // 16384
    const int M = (out_size - rows) / (B * C);    // 3584

    char* ws = (char*)d_ws;
    unsigned short* w1p = (unsigned short*)(ws);              //   393,216 B
    unsigned short* w2p = (unsigned short*)(ws + 393216);     //   393,216 B
    short* idxT         = (short*)(ws + 786432);              //   229,376 B

    prep<<<288, 512, 0, stream>>>(w1, w2, w1p, w2p, tgt, idxT, M);
    // 288 fused-conv blocks + 1792 gather blocks
    fused<<<2080, 512, 0, stream>>>(x, w1p, b1, g1, be1, w2p, b2, g2, be2,
                                    lw, lb, out + (size_t)B * M * C, idxT, out, M);
}